// Round 3
// baseline (344.206 us; speedup 1.0000x reference)
//
#include <hip/hip_runtime.h>
#include <hip/hip_bf16.h>
#include <stdint.h>

typedef unsigned short u16;
typedef __attribute__((ext_vector_type(8))) short bf16x8;
typedef __attribute__((ext_vector_type(4))) float f32x4;
typedef __attribute__((ext_vector_type(4))) unsigned short u16x4;

#define DEVI static __device__ __forceinline__

DEVI u16 f2bf(float f) {
    unsigned int u = __builtin_bit_cast(unsigned int, f);
    return (u16)((u + 0x7fffu + ((u >> 16) & 1u)) >> 16);
}

DEVI void async_copy16(const void* g, void* l) {
    __builtin_amdgcn_global_load_lds((const __attribute__((address_space(1))) void*)g,
                                     (__attribute__((address_space(3))) void*)l,
                                     16, 0, 0);
}

// ---------------- weight transpose + f32->bf16 convert: src[K][N] -> dst[N][K] ----------------
__global__ __launch_bounds__(256) void tcvt_kernel(const float* __restrict__ src,
                                                   u16* __restrict__ dst,
                                                   int K, int N) {
    __shared__ float tile[32][33];
    const int k0 = blockIdx.x * 32, n0 = blockIdx.y * 32;
    const int t = threadIdx.x;
    const int c = t & 31, r0 = t >> 5;
#pragma unroll
    for (int p = 0; p < 4; ++p) {
        const int r = r0 + p * 8;
        tile[r][c] = src[(size_t)(k0 + r) * N + n0 + c];
    }
    __syncthreads();
#pragma unroll
    for (int p = 0; p < 4; ++p) {
        const int r = r0 + p * 8;
        dst[(size_t)(n0 + r) * K + k0 + c] = f2bf(tile[c][r]);
    }
}

// ---------------- LayerNorm (f32 in) -> bf16 out ----------------
__global__ __launch_bounds__(256) void ln_kernel(const float* __restrict__ x,
                                                 const float* __restrict__ gw,
                                                 const float* __restrict__ bw,
                                                 u16* __restrict__ out) {
    const int row = blockIdx.x;
    const int t = threadIdx.x;
    const float4 v = ((const float4*)(x + (size_t)row * 1024))[t];
    float s  = v.x + v.y + v.z + v.w;
    float ss = v.x * v.x + v.y * v.y + v.z * v.z + v.w * v.w;
#pragma unroll
    for (int off = 32; off > 0; off >>= 1) {
        s  += __shfl_down(s, off);
        ss += __shfl_down(ss, off);
    }
    __shared__ float red[8];
    const int wv = t >> 6;
    if ((t & 63) == 0) { red[wv] = s; red[4 + wv] = ss; }
    __syncthreads();
    if (t == 0) {
        red[0] = red[0] + red[1] + red[2] + red[3];
        red[4] = red[4] + red[5] + red[6] + red[7];
    }
    __syncthreads();
    const float mean = red[0] * (1.0f / 1024.0f);
    const float var  = red[4] * (1.0f / 1024.0f) - mean * mean;
    const float rstd = rsqrtf(var + 1e-5f);
    const float4 gv = ((const float4*)gw)[t];
    const float4 bv = ((const float4*)bw)[t];
    u16x4 o;
    o[0] = f2bf((v.x - mean) * rstd * gv.x + bv.x);
    o[1] = f2bf((v.y - mean) * rstd * gv.y + bv.y);
    o[2] = f2bf((v.z - mean) * rstd * gv.z + bv.z);
    o[3] = f2bf((v.w - mean) * rstd * gv.w + bv.w);
    ((u16x4*)out)[(size_t)row * 256 + t] = o;
}

// ================= 256x256 8-phase GEMM (m201-style template, plain HIP) =================
// A [M][K] bf16, Bt [N][K] bf16. 512 threads (8 waves, 2M x 4N), BK=64, dbuf LDS 128 KiB.
// LDS per operand-buffer: 2 k-half regions of 16 KiB; each k-half = 16 subtiles [16 rows][32 cols]
// with st_16x32 XOR swizzle (byte bit5 ^= row bit3), pre-swizzled on the global source (rule 21).
// EPI 0: QKV scatter (q*0.125 / k / vt). EPI 2: gelu->bf16. EPI 4: f32 partial (split-K).
DEVI void stage_half(const char* g, size_t ldb, char* ldsbase, int lane, int wv) {
    const int colsw = ((lane & 3) << 4) ^ (lane & 32);  // pre-swizzled source column bytes
    const int rl = lane >> 2;
#pragma unroll
    for (int i = 0; i < 2; ++i) {
        const int c = wv + i * 8;   // subtile/chunk 0..15
        async_copy16(g + (size_t)(c * 16 + rl) * ldb + colsw, ldsbase + c * 1024);
    }
}

template <int EPI, int SPLITK>
__global__ __launch_bounds__(512, 2) void gemm8p(const u16* __restrict__ A,
                                                 const u16* __restrict__ Bt,
                                                 const float* __restrict__ bias,
                                                 void* __restrict__ out0,
                                                 void* __restrict__ out1,
                                                 void* __restrict__ out2,
                                                 int M, int N, int K) {
    __shared__ __align__(16) char lds[131072];
    const int tid = threadIdx.x;
    const int lane = tid & 63, wv = tid >> 6;
    const int wr = wv >> 2, wc = wv & 3;        // 2M x 4N waves
    const int g = lane >> 4, qq = lane & 15;
    const int rdoff = qq * 64 + ((g * 16) ^ ((qq & 8) << 2));  // swizzled read offset in subtile

    // XCD-aware bijective swizzle (all grids are multiples of 8)
    const int nwg = gridDim.x;
    int id = blockIdx.x;
    id = (id & 7) * (nwg >> 3) + (id >> 3);
    const int MT = M >> 8, NTn = N >> 8;
    const int slice = id / (MT * NTn);
    const int r2 = id % (MT * NTn);
    const int m0 = (r2 % MT) << 8;
    const int n0 = (r2 / MT) << 8;
    const int Ks = K / SPLITK;
    const int NT = Ks >> 6;                      // 64-wide K tiles in this slice
    const size_t ldb = (size_t)K * 2;

    const char* pa = (const char*)A + (size_t)m0 * ldb + (size_t)slice * Ks * 2;
    const char* pb = (const char*)Bt + (size_t)n0 * ldb + (size_t)slice * Ks * 2;

    f32x4 acc[8][4] = {};

    // prologue: tile0 kh0, tile0 kh1, tile1 kh0
    stage_half(pa, ldb, lds, lane, wv);
    stage_half(pb, ldb, lds + 32768, lane, wv);
    stage_half(pa + 64, ldb, lds + 16384, lane, wv);
    stage_half(pb + 64, ldb, lds + 49152, lane, wv);
    if (NT > 1) {
        stage_half(pa + 128, ldb, lds + 65536, lane, wv);
        stage_half(pb + 128, ldb, lds + 98304, lane, wv);
    }
    asm volatile("s_waitcnt vmcnt(4)" ::: "memory");
    asm volatile("s_barrier" ::: "memory");

    for (int t = 0; t < NT; ++t) {
        const int buf = t & 1;
        char* curA = lds + buf * 65536;
        char* curB = curA + 32768;
        char* nxtA = lds + (buf ^ 1) * 65536;
        char* nxtB = nxtA + 32768;
#pragma unroll
        for (int ks = 0; ks < 2; ++ks) {
            bf16x8 fb[4];
#pragma unroll
            for (int mh = 0; mh < 2; ++mh) {
                // stage schedule: a: A(t+1)kh1, b: B(t+1)kh1, c: A(t+2)kh0, d: B(t+2)kh0
                if (ks == 0 && mh == 0) { if (t + 1 < NT) stage_half(pa + (size_t)(t + 1) * 128 + 64, ldb, nxtA + 16384, lane, wv); }
                if (ks == 0 && mh == 1) { if (t + 1 < NT) stage_half(pb + (size_t)(t + 1) * 128 + 64, ldb, nxtB + 16384, lane, wv); }
                if (ks == 1 && mh == 0) { if (t + 2 < NT) stage_half(pa + (size_t)(t + 2) * 128, ldb, curA, lane, wv); }
                if (ks == 1 && mh == 1) { if (t + 2 < NT) stage_half(pb + (size_t)(t + 2) * 128, ldb, curB, lane, wv); }
                // ds reads for this phase
                if (mh == 0) {
#pragma unroll
                    for (int fn = 0; fn < 4; ++fn)
                        fb[fn] = *(const bf16x8*)(curB + (ks * 16 + wc * 4 + fn) * 1024 + rdoff);
                }
                bf16x8 fa[4];
#pragma unroll
                for (int i = 0; i < 4; ++i)
                    fa[i] = *(const bf16x8*)(curA + (ks * 16 + wr * 8 + mh * 4 + i) * 1024 + rdoff);
                asm volatile("s_barrier" ::: "memory");
                asm volatile("s_waitcnt lgkmcnt(0)" ::: "memory");
                __builtin_amdgcn_sched_barrier(0);
                __builtin_amdgcn_s_setprio(1);
#pragma unroll
                for (int fn = 0; fn < 4; ++fn)
#pragma unroll
                    for (int i = 0; i < 4; ++i)
                        acc[mh * 4 + i][fn] = __builtin_amdgcn_mfma_f32_16x16x32_bf16(
                            fa[i], fb[fn], acc[mh * 4 + i][fn], 0, 0, 0);
                __builtin_amdgcn_s_setprio(0);
                __builtin_amdgcn_sched_barrier(0);
                if (ks == 1 && mh == 1) {
                    if (t + 2 < NT) { asm volatile("s_waitcnt vmcnt(4)" ::: "memory"); }
                    else            { asm volatile("s_waitcnt vmcnt(0)" ::: "memory"); }
                }
                asm volatile("s_barrier" ::: "memory");
            }
        }
    }

    // epilogue: lane holds D[g*4+r][qq] per 16x16 fragment
#pragma unroll
    for (int fm = 0; fm < 8; ++fm) {
#pragma unroll
        for (int fn = 0; fn < 4; ++fn) {
            const int mrow = m0 + wr * 128 + fm * 16 + g * 4;
            const int ncol = n0 + wc * 64 + fn * 16 + qq;
            if constexpr (EPI == 0) {
                const float bs = bias[ncol];
                const int sec = ncol >> 10;
                const int hd_ = ncol & 1023;
                const int hh = hd_ >> 6, dd = hd_ & 63;
                if (sec == 2) {
                    const int b_ = mrow >> 11, l_ = mrow & 2047;
                    u16x4 pk;
#pragma unroll
                    for (int r = 0; r < 4; ++r) pk[r] = f2bf(acc[fm][fn][r] + bs);
                    *(u16x4*)((u16*)out2 + ((size_t)((b_ * 16 + hh) * 64 + dd)) * 2048 + l_) = pk;
                } else {
                    u16* dst = (sec == 0) ? (u16*)out0 : (u16*)out1;
                    const float sc = (sec == 0) ? 0.125f : 1.0f;
#pragma unroll
                    for (int r = 0; r < 4; ++r) {
                        const int mr = mrow + r;
                        const int b_ = mr >> 11, l_ = mr & 2047;
                        dst[((size_t)((b_ * 16 + hh) * 2048 + l_)) * 64 + dd] =
                            f2bf((acc[fm][fn][r] + bs) * sc);
                    }
                }
            } else if constexpr (EPI == 2) {
                const float bs = bias[ncol];
                u16* dst = (u16*)out0;
#pragma unroll
                for (int r = 0; r < 4; ++r) {
                    float v = acc[fm][fn][r] + bs;
                    v = 0.5f * v * (1.0f + erff(v * 0.70710678118f));
                    dst[(size_t)(mrow + r) * N + ncol] = f2bf(v);
                }
            } else {  // EPI 4: raw f32 partial for split-K
                float* dst = (float*)out0 + (size_t)slice * M * N;
#pragma unroll
                for (int r = 0; r < 4; ++r)
                    dst[(size_t)(mrow + r) * N + ncol] = acc[fm][fn][r];
            }
        }
    }
}

// split-K=4 reduce + bias + residual -> f32 out (M=4096, N=1024)
__global__ __launch_bounds__(256) void reduce4_kernel(const float* __restrict__ p,
                                                      const float* __restrict__ bias,
                                                      const float* __restrict__ res,
                                                      float* __restrict__ out) {
    const size_t i = (size_t)blockIdx.x * 256 + threadIdx.x;   // float4 index
    const float4 a = ((const float4*)p)[i];
    const float4 b = ((const float4*)p)[i + 1048576];
    const float4 c = ((const float4*)p)[i + 2097152];
    const float4 d = ((const float4*)p)[i + 3145728];
    const float4 r = ((const float4*)res)[i];
    const float4 bs = ((const float4*)bias)[i & 255];
    float4 o;
    o.x = a.x + b.x + c.x + d.x + r.x + bs.x;
    o.y = a.y + b.y + c.y + d.y + r.y + bs.y;
    o.z = a.z + b.z + c.z + d.z + r.z + bs.z;
    o.w = a.w + b.w + c.w + d.w + r.w + bs.w;
    ((float4*)out)[i] = o;
}

// ---------------- old 2-phase GEMM (kept for proj + FC2 fallback) ----------------
// EPI 1: f32 val+bias+res. EPI 3: f32 val+bias+res (FC2 fallback).
template <int BM, int BN, int EPI>
__global__ __launch_bounds__(256, 2) void gemm_bf16(const u16* __restrict__ A,
                                                    const u16* __restrict__ Bt,
                                                    const float* __restrict__ bias,
                                                    const float* __restrict__ res,
                                                    void* __restrict__ out0,
                                                    int M, int N, int K) {
    constexpr int WM = BM / 2, WN = BN / 2;
    constexpr int FM = WM / 16, FN = WN / 16;
    __shared__ __align__(16) short Asm[BM * 32];
    __shared__ __align__(16) short Bsm[BN * 32];
    const int tid = threadIdx.x;
    const int lane = tid & 63, wv = tid >> 6;
    const int wr = wv >> 1, wc = wv & 1;
    const int g = lane >> 4, qq = lane & 15;
    const int n0 = blockIdx.x * BN, m0 = blockIdx.y * BM;

    f32x4 acc[FM][FN] = {};
    const char* srcA = (const char*)A + ((size_t)m0 * K) * 2;
    const char* srcB = (const char*)Bt + ((size_t)n0 * K) * 2;
    const size_t strideAB = (size_t)K * 2;

    for (int k0 = 0; k0 < K; k0 += 32) {
#pragma unroll
        for (int i = 0; i < BM * 64 / 4096; ++i) {
            const int b = i * 4096 + wv * 1024 + lane * 16;
            const int row = b >> 6, colb = b & 63;
            async_copy16(srcA + (size_t)row * strideAB + (size_t)k0 * 2 + colb,
                         (char*)Asm + i * 4096 + wv * 1024);
        }
#pragma unroll
        for (int i = 0; i < BN * 64 / 4096; ++i) {
            const int b = i * 4096 + wv * 1024 + lane * 16;
            const int row = b >> 6, colb = b & 63;
            async_copy16(srcB + (size_t)row * strideAB + (size_t)k0 * 2 + colb,
                         (char*)Bsm + i * 4096 + wv * 1024);
        }
        __syncthreads();
        bf16x8 af[FM], bfr[FN];
#pragma unroll
        for (int fm = 0; fm < FM; ++fm)
            af[fm] = *(const bf16x8*)(&Asm[(wr * WM + fm * 16 + qq) * 32 + g * 8]);
#pragma unroll
        for (int fn = 0; fn < FN; ++fn)
            bfr[fn] = *(const bf16x8*)(&Bsm[(wc * WN + fn * 16 + qq) * 32 + g * 8]);
#pragma unroll
        for (int fm = 0; fm < FM; ++fm)
#pragma unroll
            for (int fn = 0; fn < FN; ++fn)
                acc[fm][fn] = __builtin_amdgcn_mfma_f32_16x16x32_bf16(af[fm], bfr[fn],
                                                                      acc[fm][fn], 0, 0, 0);
        __syncthreads();
    }

    const int g4 = g * 4;
#pragma unroll
    for (int fm = 0; fm < FM; ++fm) {
#pragma unroll
        for (int fn = 0; fn < FN; ++fn) {
            const int mrow = m0 + wr * WM + fm * 16 + g4;
            const int ncol = n0 + wc * WN + fn * 16 + qq;
            const float bs = bias[ncol];
            float* dst = (float*)out0;
#pragma unroll
            for (int r = 0; r < 4; ++r) {
                const int mr = mrow + r;
                dst[(size_t)mr * N + ncol] = acc[fm][fn][r] + bs + res[(size_t)mr * N + ncol];
            }
        }
    }
}

// ---------------- causal flash attention (unchanged from round 1) ----------------
DEVI void stage_kv(const char* kbase, const char* vbase, int key0,
                   u16* ksm, u16* vsm, int wv, int lane) {
#pragma unroll
    for (int i = 0; i < 2; ++i) {
        const int c = wv + i * 4;
        const int off = c * 1024 + lane * 16;
        const int row = off >> 7;
        const int scol = (off & 127) ^ ((row & 7) << 4);
        async_copy16(kbase + (size_t)key0 * 128 + (size_t)row * 128 + scol,
                     (char*)ksm + c * 1024);
    }
#pragma unroll
    for (int i = 0; i < 2; ++i) {
        const int c = wv + i * 4;
        const int row = c * 8 + (lane >> 3);
        const int scol = ((lane & 7) * 16) ^ ((row & 7) << 4);
        async_copy16(vbase + (size_t)row * 4096 + (size_t)key0 * 2 + scol,
                     (char*)vsm + c * 1024);
    }
}

__global__ __launch_bounds__(256, 3) void attn_kernel(const u16* __restrict__ Q,
                                                      const u16* __restrict__ Kk,
                                                      const u16* __restrict__ Vt,
                                                      u16* __restrict__ Y) {
    const int bh = blockIdx.y;
    const int b_ = bh >> 4, hh = bh & 15;
    const int qb = gridDim.x - 1 - blockIdx.x;
    const int tid = threadIdx.x;
    const int wv = tid >> 6, lane = tid & 63;
    const int g = lane >> 4, qi = lane & 15;
    const int xsw = (qi & 7) << 4;
    const int q0 = qb * 64 + wv * 16;
    const int qg = q0 + qi;

    __shared__ __align__(16) u16 Ksm[2][4096];
    __shared__ __align__(16) u16 Vsm[2][4096];
    __shared__ __align__(16) u16 Pl[4][16][72];

    const u16*  Qb = Q + ((size_t)bh * 2048 + q0) * 64;
    const char* Kb = (const char*)(Kk + (size_t)bh * 2048 * 64);
    const char* Vb = (const char*)(Vt + (size_t)bh * 64 * 2048);

    bf16x8 qf[2];
#pragma unroll
    for (int ks = 0; ks < 2; ++ks)
        qf[ks] = *(const bf16x8*)(Qb + qi * 64 + ks * 32 + g * 8);

    f32x4 oacc[4] = {};
    float m_run = -1e30f, l_run = 0.0f;
    const int ntile = qb + 1;

    stage_kv(Kb, Vb, 0, Ksm[0], Vsm[0], wv, lane);
    __syncthreads();

    int cur = 0;
    for (int kt = 0; kt < ntile; ++kt) {
        const int key0 = kt * 64;
        if (kt + 1 < ntile)
            stage_kv(Kb, Vb, key0 + 64, Ksm[cur ^ 1], Vsm[cur ^ 1], wv, lane);

        f32x4 sacc[4] = {};
#pragma unroll
        for (int ks = 0; ks < 2; ++ks) {
#pragma unroll
            for (int kc = 0; kc < 4; ++kc) {
                const int rk = kc * 16 + qi;
                const bf16x8 ak = *(const bf16x8*)((const char*)Ksm[cur] + rk * 128 +
                                                   ((ks * 64 + g * 16) ^ xsw));
                sacc[kc] = __builtin_amdgcn_mfma_f32_16x16x32_bf16(ak, qf[ks], sacc[kc], 0, 0, 0);
            }
        }

        float p[4][4];
        float mymax = -1e30f;
        if (kt == ntile - 1) {
#pragma unroll
            for (int kc = 0; kc < 4; ++kc) {
#pragma unroll
                for (int r = 0; r < 4; ++r) {
                    const int key = key0 + kc * 16 + g * 4 + r;
                    float sv = sacc[kc][r];
                    if (key > qg) sv = -__builtin_inff();
                    p[kc][r] = sv;
                    mymax = fmaxf(mymax, sv);
                }
            }
        } else {
#pragma unroll
            for (int kc = 0; kc < 4; ++kc) {
#pragma unroll
                for (int r = 0; r < 4; ++r) {
                    p[kc][r] = sacc[kc][r];
                    mymax = fmaxf(mymax, sacc[kc][r]);
                }
            }
        }
        mymax = fmaxf(mymax, __shfl_xor(mymax, 16));
        mymax = fmaxf(mymax, __shfl_xor(mymax, 32));
        const float m_new = fmaxf(m_run, mymax);
        const float alpha = __expf(m_run - m_new);
        float lsum = 0.0f;
#pragma unroll
        for (int kc = 0; kc < 4; ++kc) {
#pragma unroll
            for (int r = 0; r < 4; ++r) {
                const float e = __expf(p[kc][r] - m_new);
                p[kc][r] = e;
                lsum += e;
            }
        }
        lsum += __shfl_xor(lsum, 16);
        lsum += __shfl_xor(lsum, 32);
        l_run = l_run * alpha + lsum;
        m_run = m_new;
#pragma unroll
        for (int c = 0; c < 4; ++c) {
#pragma unroll
            for (int r = 0; r < 4; ++r) oacc[c][r] *= alpha;
        }
#pragma unroll
        for (int kc = 0; kc < 4; ++kc) {
            u16x4 pk;
#pragma unroll
            for (int r = 0; r < 4; ++r) pk[r] = f2bf(p[kc][r]);
            *(u16x4*)(&Pl[wv][qi][kc * 16 + g * 4]) = pk;
        }
        bf16x8 pb[2];
#pragma unroll
        for (int ks = 0; ks < 2; ++ks)
            pb[ks] = *(const bf16x8*)(&Pl[wv][qi][ks * 32 + g * 8]);
#pragma unroll
        for (int ks = 0; ks < 2; ++ks) {
#pragma unroll
            for (int c = 0; c < 4; ++c) {
                const int rv = c * 16 + qi;
                const bf16x8 av = *(const bf16x8*)((const char*)Vsm[cur] + rv * 128 +
                                                   ((ks * 64 + g * 16) ^ xsw));
                oacc[c] = __builtin_amdgcn_mfma_f32_16x16x32_bf16(av, pb[ks], oacc[c], 0, 0, 0);
            }
        }
        __syncthreads();
        cur ^= 1;
    }

    const float inv = 1.0f / l_run;
#pragma unroll
    for (int c = 0; c < 4; ++c) {
        u16x4 o;
#pragma unroll
        for (int r = 0; r < 4; ++r) o[r] = f2bf(oacc[c][r] * inv);
        *(u16x4*)(&Y[((size_t)(b_ * 2048 + qg)) * 1024 + hh * 64 + c * 16 + g * 4]) = o;
    }
}

// ---------------- host ----------------
extern "C" void kernel_launch(void* const* d_in, const int* in_sizes, int n_in,
                              void* d_out, int out_size, void* d_ws, size_t ws_size,
                              hipStream_t stream) {
    (void)in_sizes; (void)n_in; (void)out_size;
    const float* x      = (const float*)d_in[0];
    const float* w_qkv  = (const float*)d_in[2];
    const float* b_qkv  = (const float*)d_in[3];
    const float* w_proj = (const float*)d_in[4];
    const float* b_proj = (const float*)d_in[5];
    const float* w_fc1  = (const float*)d_in[6];
    const float* b_fc1  = (const float*)d_in[7];
    const float* w_fc2  = (const float*)d_in[8];
    const float* b_fc2  = (const float*)d_in[9];
    const float* g1     = (const float*)d_in[10];
    const float* be1    = (const float*)d_in[11];
    const float* g2     = (const float*)d_in[12];
    const float* be2    = (const float*)d_in[13];

    char* ws = (char*)d_ws;
    size_t off = 0;
    auto alloc = [&](size_t bytes) { size_t r = off; off += (bytes + 255) & ~(size_t)255; return r; };
    u16*   wt_qkv = (u16*)(ws + alloc((size_t)3072 * 1024 * 2));
    u16*   wt_prj = (u16*)(ws + alloc((size_t)1024 * 1024 * 2));
    u16*   wt_fc1 = (u16*)(ws + alloc((size_t)4096 * 1024 * 2));
    u16*   wt_fc2 = (u16*)(ws + alloc((size_t)1024 * 4096 * 2));
    u16*   hbuf   = (u16*)(ws + alloc((size_t)4096 * 1024 * 2));
    float* x1     = (float*)(ws + alloc((size_t)4096 * 1024 * 4));
    char*  big    = ws + alloc((size_t)33554432);
    u16* qb  = (u16*)(big);
    u16* kb  = (u16*)(big + 8388608);
    u16* vtb = (u16*)(big + 16777216);
    u16* yb  = (u16*)(big + 25165824);
    u16* act = (u16*)(big);
    if (off > ws_size) return;
    const size_t part_need = (size_t)4 * 4096 * 1024 * 4;
    const bool has_part = (ws_size - off) >= part_need;
    float* part = (float*)(ws + off);

    const dim3 blk(256);
    tcvt_kernel<<<dim3(32, 96), blk, 0, stream>>>(w_qkv, wt_qkv, 1024, 3072);
    tcvt_kernel<<<dim3(32, 32), blk, 0, stream>>>(w_proj, wt_prj, 1024, 1024);
    tcvt_kernel<<<dim3(32, 128), blk, 0, stream>>>(w_fc1, wt_fc1, 1024, 4096);
    tcvt_kernel<<<dim3(128, 32), blk, 0, stream>>>(w_fc2, wt_fc2, 4096, 1024);

    ln_kernel<<<dim3(4096), blk, 0, stream>>>(x, g1, be1, hbuf);
    // QKV: 8-phase 256^2, grid 16*12=192
    gemm8p<0, 1><<<dim3(192), dim3(512), 0, stream>>>(hbuf, wt_qkv, b_qkv,
                                                      qb, kb, vtb, 4096, 3072, 1024);
    attn_kernel<<<dim3(32, 32), blk, 0, stream>>>(qb, kb, vtb, yb);
    // proj + residual (old path)
    gemm_bf16<64, 128, 1><<<dim3(8, 64), blk, 0, stream>>>(yb, wt_prj, b_proj, x,
                                                           x1, 4096, 1024, 1024);
    ln_kernel<<<dim3(4096), blk, 0, stream>>>(x1, g2, be2, hbuf);
    // FC1 + GELU: 8-phase, grid 256
    gemm8p<2, 1><<<dim3(256), dim3(512), 0, stream>>>(hbuf, wt_fc1, b_fc1,
                                                      act, nullptr, nullptr, 4096, 4096, 1024);
    if (has_part) {
        // FC2 split-K=4: grid 16*4*4=256, then fused reduce+bias+residual
        gemm8p<4, 4><<<dim3(256), dim3(512), 0, stream>>>(act, wt_fc2, nullptr,
                                                          part, nullptr, nullptr, 4096, 1024, 4096);
        reduce4_kernel<<<dim3(4096), blk, 0, stream>>>(part, b_fc2, x1, (float*)d_out);
    } else {
        gemm_bf16<64, 128, 3><<<dim3(8, 64), blk, 0, stream>>>(act, wt_fc2, b_fc2, x1,
                                                               (float*)d_out, 4096, 1024, 4096);
    }
}

// Round 4
// 340.034 us; speedup vs baseline: 1.0123x; 1.0123x over previous
//
#include <hip/hip_runtime.h>
#include <hip/hip_bf16.h>
#include <stdint.h>

typedef unsigned short u16;
typedef __attribute__((ext_vector_type(8))) short bf16x8;
typedef __attribute__((ext_vector_type(4))) float f32x4;
typedef __attribute__((ext_vector_type(4))) unsigned short u16x4;

#define DEVI static __device__ __forceinline__

DEVI u16 f2bf(float f) {
    unsigned int u = __builtin_bit_cast(unsigned int, f);
    return (u16)((u + 0x7fffu + ((u >> 16) & 1u)) >> 16);
}

DEVI void async_copy16(const void* g, void* l) {
    __builtin_amdgcn_global_load_lds((const __attribute__((address_space(1))) void*)g,
                                     (__attribute__((address_space(3))) void*)l,
                                     16, 0, 0);
}

// ---------------- weight transpose + f32->bf16 convert: src[K][N] -> dst[N][K] ----------------
__global__ __launch_bounds__(256) void tcvt_kernel(const float* __restrict__ src,
                                                   u16* __restrict__ dst,
                                                   int K, int N) {
    __shared__ float tile[32][33];
    const int k0 = blockIdx.x * 32, n0 = blockIdx.y * 32;
    const int t = threadIdx.x;
    const int c = t & 31, r0 = t >> 5;
#pragma unroll
    for (int p = 0; p < 4; ++p) {
        const int r = r0 + p * 8;
        tile[r][c] = src[(size_t)(k0 + r) * N + n0 + c];
    }
    __syncthreads();
#pragma unroll
    for (int p = 0; p < 4; ++p) {
        const int r = r0 + p * 8;
        dst[(size_t)(n0 + r) * K + k0 + c] = f2bf(tile[c][r]);
    }
}

// ---------------- LayerNorm (f32 in) -> bf16 out ----------------
__global__ __launch_bounds__(256) void ln_kernel(const float* __restrict__ x,
                                                 const float* __restrict__ gw,
                                                 const float* __restrict__ bw,
                                                 u16* __restrict__ out) {
    const int row = blockIdx.x;
    const int t = threadIdx.x;
    const float4 v = ((const float4*)(x + (size_t)row * 1024))[t];
    float s  = v.x + v.y + v.z + v.w;
    float ss = v.x * v.x + v.y * v.y + v.z * v.z + v.w * v.w;
#pragma unroll
    for (int off = 32; off > 0; off >>= 1) {
        s  += __shfl_down(s, off);
        ss += __shfl_down(ss, off);
    }
    __shared__ float red[8];
    const int wv = t >> 6;
    if ((t & 63) == 0) { red[wv] = s; red[4 + wv] = ss; }
    __syncthreads();
    if (t == 0) {
        red[0] = red[0] + red[1] + red[2] + red[3];
        red[4] = red[4] + red[5] + red[6] + red[7];
    }
    __syncthreads();
    const float mean = red[0] * (1.0f / 1024.0f);
    const float var  = red[4] * (1.0f / 1024.0f) - mean * mean;
    const float rstd = rsqrtf(var + 1e-5f);
    const float4 gv = ((const float4*)gw)[t];
    const float4 bv = ((const float4*)bw)[t];
    u16x4 o;
    o[0] = f2bf((v.x - mean) * rstd * gv.x + bv.x);
    o[1] = f2bf((v.y - mean) * rstd * gv.y + bv.y);
    o[2] = f2bf((v.z - mean) * rstd * gv.z + bv.z);
    o[3] = f2bf((v.w - mean) * rstd * gv.w + bv.w);
    ((u16x4*)out)[(size_t)row * 256 + t] = o;
}

// ================= 256x256 minimum-2-phase GEMM (T3 recipe) =================
// A [M][K] bf16, Bt [N][K] bf16. 512 threads (8 waves, 2M x 4N), BK=64, dbuf LDS 128 KiB.
// Buffer region (64 KiB): A kh0 16K | A kh1 16K | B kh0 16K | B kh1 16K.
// Each 16K half = 16 subtiles [16 rows][32 cols] with st_16x32 XOR swizzle
// (byte bit5 ^= row bit3), applied via pre-swizzled global source (rule 21) —
// addressing identical to round 3 (HW-verified: correct + 0 bank conflicts).
// Schedule: STAGE(t+1) -> ds_read+MFMA on cur -> ONE vmcnt(0)+barrier per tile.
DEVI void stage_half(const char* g, size_t ldb, char* ldsbase, int lane, int wv) {
    const int colsw = ((lane & 3) << 4) ^ (lane & 32);  // pre-swizzled source column bytes
    const int rl = lane >> 2;
#pragma unroll
    for (int i = 0; i < 2; ++i) {
        const int c = wv + i * 8;   // subtile 0..15
        async_copy16(g + (size_t)(c * 16 + rl) * ldb + colsw, ldsbase + c * 1024);
    }
}

// EPI 0: QKV scatter (q*0.125 / k / vt). EPI 2: gelu->bf16. EPI 4: f32 partial (split-K).
template <int EPI, int SPLITK>
__global__ __launch_bounds__(512, 2) void gemm2p(const u16* __restrict__ A,
                                                 const u16* __restrict__ Bt,
                                                 const float* __restrict__ bias,
                                                 void* __restrict__ out0,
                                                 void* __restrict__ out1,
                                                 void* __restrict__ out2,
                                                 int M, int N, int K) {
    __shared__ __align__(16) char lds[131072];
    const int tid = threadIdx.x;
    const int lane = tid & 63, wv = tid >> 6;
    const int wr = wv >> 2, wc = wv & 3;        // 2M x 4N waves
    const int g = lane >> 4, qq = lane & 15;
    const int rdoff = qq * 64 + ((g * 16) ^ ((qq & 8) << 2));  // swizzled read offset in subtile

    // XCD-aware bijective swizzle (all grids used are multiples of 8)
    const int nwg = gridDim.x;
    int id = blockIdx.x;
    id = (id & 7) * (nwg >> 3) + (id >> 3);
    const int MT = M >> 8, NTn = N >> 8;
    const int slice = id / (MT * NTn);
    const int r2 = id % (MT * NTn);
    const int m0 = (r2 % MT) << 8;
    const int n0 = (r2 / MT) << 8;
    const int Ks = K / SPLITK;
    const int NT = Ks >> 6;                      // 64-wide K tiles in this slice
    const size_t ldb = (size_t)K * 2;

    const char* pa = (const char*)A + (size_t)m0 * ldb + (size_t)slice * Ks * 2;
    const char* pb = (const char*)Bt + (size_t)n0 * ldb + (size_t)slice * Ks * 2;

    f32x4 acc[8][4] = {};

    // prologue: stage tile 0 into buffer 0
    stage_half(pa,      ldb, lds,         lane, wv);
    stage_half(pa + 64, ldb, lds + 16384, lane, wv);
    stage_half(pb,      ldb, lds + 32768, lane, wv);
    stage_half(pb + 64, ldb, lds + 49152, lane, wv);
    asm volatile("s_waitcnt vmcnt(0)" ::: "memory");
    __builtin_amdgcn_s_barrier();

    for (int t = 0; t < NT; ++t) {
        char* cur = lds + (t & 1) * 65536;
        char* nxt = lds + ((t & 1) ^ 1) * 65536;
        if (t + 1 < NT) {
            const char* qa = pa + (size_t)(t + 1) * 128;
            const char* qb = pb + (size_t)(t + 1) * 128;
            stage_half(qa,      ldb, nxt,         lane, wv);
            stage_half(qa + 64, ldb, nxt + 16384, lane, wv);
            stage_half(qb,      ldb, nxt + 32768, lane, wv);
            stage_half(qb + 64, ldb, nxt + 49152, lane, wv);
        }
#pragma unroll
        for (int ks = 0; ks < 2; ++ks) {
            bf16x8 fb[4], fa[8];
#pragma unroll
            for (int fn = 0; fn < 4; ++fn)
                fb[fn] = *(const bf16x8*)(cur + 32768 + (ks * 16 + wc * 4 + fn) * 1024 + rdoff);
#pragma unroll
            for (int i = 0; i < 8; ++i)
                fa[i] = *(const bf16x8*)(cur + (ks * 16 + wr * 8 + i) * 1024 + rdoff);
            asm volatile("s_waitcnt lgkmcnt(0)" ::: "memory");
            __builtin_amdgcn_sched_barrier(0);
            __builtin_amdgcn_s_setprio(1);
#pragma unroll
            for (int fn = 0; fn < 4; ++fn)
#pragma unroll
                for (int i = 0; i < 8; ++i)
                    acc[i][fn] = __builtin_amdgcn_mfma_f32_16x16x32_bf16(fa[i], fb[fn],
                                                                         acc[i][fn], 0, 0, 0);
            __builtin_amdgcn_s_setprio(0);
        }
        asm volatile("s_waitcnt vmcnt(0)" ::: "memory");
        __builtin_amdgcn_s_barrier();
    }

    // epilogue: lane holds D[g*4+r][qq] per 16x16 fragment
#pragma unroll
    for (int fm = 0; fm < 8; ++fm) {
#pragma unroll
        for (int fn = 0; fn < 4; ++fn) {
            const int mrow = m0 + wr * 128 + fm * 16 + g * 4;
            const int ncol = n0 + wc * 64 + fn * 16 + qq;
            if constexpr (EPI == 0) {
                const float bs = bias[ncol];
                const int sec = ncol >> 10;
                const int hd_ = ncol & 1023;
                const int hh = hd_ >> 6, dd = hd_ & 63;
                if (sec == 2) {
                    const int b_ = mrow >> 11, l_ = mrow & 2047;
                    u16x4 pk;
#pragma unroll
                    for (int r = 0; r < 4; ++r) pk[r] = f2bf(acc[fm][fn][r] + bs);
                    *(u16x4*)((u16*)out2 + ((size_t)((b_ * 16 + hh) * 64 + dd)) * 2048 + l_) = pk;
                } else {
                    u16* dst = (sec == 0) ? (u16*)out0 : (u16*)out1;
                    const float sc = (sec == 0) ? 0.125f : 1.0f;
#pragma unroll
                    for (int r = 0; r < 4; ++r) {
                        const int mr = mrow + r;
                        const int b_ = mr >> 11, l_ = mr & 2047;
                        dst[((size_t)((b_ * 16 + hh) * 2048 + l_)) * 64 + dd] =
                            f2bf((acc[fm][fn][r] + bs) * sc);
                    }
                }
            } else if constexpr (EPI == 2) {
                const float bs = bias[ncol];
                u16* dst = (u16*)out0;
#pragma unroll
                for (int r = 0; r < 4; ++r) {
                    float v = acc[fm][fn][r] + bs;
                    v = 0.5f * v * (1.0f + erff(v * 0.70710678118f));
                    dst[(size_t)(mrow + r) * N + ncol] = f2bf(v);
                }
            } else {  // EPI 4: raw f32 partial for split-K
                float* dst = (float*)out0 + (size_t)slice * M * N;
#pragma unroll
                for (int r = 0; r < 4; ++r)
                    dst[(size_t)(mrow + r) * N + ncol] = acc[fm][fn][r];
            }
        }
    }
}

// split-K=4 reduce + bias + residual -> f32 out (M=4096, N=1024)
__global__ __launch_bounds__(256) void reduce4_kernel(const float* __restrict__ p,
                                                      const float* __restrict__ bias,
                                                      const float* __restrict__ res,
                                                      float* __restrict__ out) {
    const size_t i = (size_t)blockIdx.x * 256 + threadIdx.x;   // float4 index
    const float4 a = ((const float4*)p)[i];
    const float4 b = ((const float4*)p)[i + 1048576];
    const float4 c = ((const float4*)p)[i + 2097152];
    const float4 d = ((const float4*)p)[i + 3145728];
    const float4 r = ((const float4*)res)[i];
    const float4 bs = ((const float4*)bias)[i & 255];
    float4 o;
    o.x = a.x + b.x + c.x + d.x + r.x + bs.x;
    o.y = a.y + b.y + c.y + d.y + r.y + bs.y;
    o.z = a.z + b.z + c.z + d.z + r.z + bs.z;
    o.w = a.w + b.w + c.w + d.w + r.w + bs.w;
    ((float4*)out)[i] = o;
}

// ---------------- old 2-phase 128-class GEMM (kept for proj + FC2 fallback) ----------------
template <int BM, int BN, int EPI>
__global__ __launch_bounds__(256, 2) void gemm_bf16(const u16* __restrict__ A,
                                                    const u16* __restrict__ Bt,
                                                    const float* __restrict__ bias,
                                                    const float* __restrict__ res,
                                                    void* __restrict__ out0,
                                                    int M, int N, int K) {
    constexpr int WM = BM / 2, WN = BN / 2;
    constexpr int FM = WM / 16, FN = WN / 16;
    __shared__ __align__(16) short Asm[BM * 32];
    __shared__ __align__(16) short Bsm[BN * 32];
    const int tid = threadIdx.x;
    const int lane = tid & 63, wv = tid >> 6;
    const int wr = wv >> 1, wc = wv & 1;
    const int g = lane >> 4, qq = lane & 15;
    const int n0 = blockIdx.x * BN, m0 = blockIdx.y * BM;

    f32x4 acc[FM][FN] = {};
    const char* srcA = (const char*)A + ((size_t)m0 * K) * 2;
    const char* srcB = (const char*)Bt + ((size_t)n0 * K) * 2;
    const size_t strideAB = (size_t)K * 2;

    for (int k0 = 0; k0 < K; k0 += 32) {
#pragma unroll
        for (int i = 0; i < BM * 64 / 4096; ++i) {
            const int b = i * 4096 + wv * 1024 + lane * 16;
            const int row = b >> 6, colb = b & 63;
            async_copy16(srcA + (size_t)row * strideAB + (size_t)k0 * 2 + colb,
                         (char*)Asm + i * 4096 + wv * 1024);
        }
#pragma unroll
        for (int i = 0; i < BN * 64 / 4096; ++i) {
            const int b = i * 4096 + wv * 1024 + lane * 16;
            const int row = b >> 6, colb = b & 63;
            async_copy16(srcB + (size_t)row * strideAB + (size_t)k0 * 2 + colb,
                         (char*)Bsm + i * 4096 + wv * 1024);
        }
        __syncthreads();
        bf16x8 af[FM], bfr[FN];
#pragma unroll
        for (int fm = 0; fm < FM; ++fm)
            af[fm] = *(const bf16x8*)(&Asm[(wr * WM + fm * 16 + qq) * 32 + g * 8]);
#pragma unroll
        for (int fn = 0; fn < FN; ++fn)
            bfr[fn] = *(const bf16x8*)(&Bsm[(wc * WN + fn * 16 + qq) * 32 + g * 8]);
#pragma unroll
        for (int fm = 0; fm < FM; ++fm)
#pragma unroll
            for (int fn = 0; fn < FN; ++fn)
                acc[fm][fn] = __builtin_amdgcn_mfma_f32_16x16x32_bf16(af[fm], bfr[fn],
                                                                      acc[fm][fn], 0, 0, 0);
        __syncthreads();
    }

    const int g4 = g * 4;
#pragma unroll
    for (int fm = 0; fm < FM; ++fm) {
#pragma unroll
        for (int fn = 0; fn < FN; ++fn) {
            const int mrow = m0 + wr * WM + fm * 16 + g4;
            const int ncol = n0 + wc * WN + fn * 16 + qq;
            const float bs = bias[ncol];
            float* dst = (float*)out0;
#pragma unroll
            for (int r = 0; r < 4; ++r) {
                const int mr = mrow + r;
                dst[(size_t)mr * N + ncol] = acc[fm][fn][r] + bs + res[(size_t)mr * N + ncol];
            }
        }
    }
}

// ---------------- causal flash attention (LDS-staged, double-buffered K/V) ----------------
DEVI void stage_kv(const char* kbase, const char* vbase, int key0,
                   u16* ksm, u16* vsm, int wv, int lane) {
#pragma unroll
    for (int i = 0; i < 2; ++i) {
        const int c = wv + i * 4;
        const int off = c * 1024 + lane * 16;
        const int row = off >> 7;
        const int scol = (off & 127) ^ ((row & 7) << 4);
        async_copy16(kbase + (size_t)key0 * 128 + (size_t)row * 128 + scol,
                     (char*)ksm + c * 1024);
    }
#pragma unroll
    for (int i = 0; i < 2; ++i) {
        const int c = wv + i * 4;
        const int row = c * 8 + (lane >> 3);
        const int scol = ((lane & 7) * 16) ^ ((row & 7) << 4);
        async_copy16(vbase + (size_t)row * 4096 + (size_t)key0 * 2 + scol,
                     (char*)vsm + c * 1024);
    }
}

__global__ __launch_bounds__(256, 3) void attn_kernel(const u16* __restrict__ Q,
                                                      const u16* __restrict__ Kk,
                                                      const u16* __restrict__ Vt,
                                                      u16* __restrict__ Y) {
    const int bh = blockIdx.y;
    const int b_ = bh >> 4, hh = bh & 15;
    const int qb = gridDim.x - 1 - blockIdx.x;
    const int tid = threadIdx.x;
    const int wv = tid >> 6, lane = tid & 63;
    const int g = lane >> 4, qi = lane & 15;
    const int xsw = (qi & 7) << 4;
    const int q0 = qb * 64 + wv * 16;
    const int qg = q0 + qi;

    __shared__ __align__(16) u16 Ksm[2][4096];
    __shared__ __align__(16) u16 Vsm[2][4096];
    __shared__ __align__(16) u16 Pl[4][16][72];

    const u16*  Qb = Q + ((size_t)bh * 2048 + q0) * 64;
    const char* Kb = (const char*)(Kk + (size_t)bh * 2048 * 64);
    const char* Vb = (const char*)(Vt + (size_t)bh * 64 * 2048);

    bf16x8 qf[2];
#pragma unroll
    for (int ks = 0; ks < 2; ++ks)
        qf[ks] = *(const bf16x8*)(Qb + qi * 64 + ks * 32 + g * 8);

    f32x4 oacc[4] = {};
    float m_run = -1e30f, l_run = 0.0f;
    const int ntile = qb + 1;

    stage_kv(Kb, Vb, 0, Ksm[0], Vsm[0], wv, lane);
    __syncthreads();

    int cur = 0;
    for (int kt = 0; kt < ntile; ++kt) {
        const int key0 = kt * 64;
        if (kt + 1 < ntile)
            stage_kv(Kb, Vb, key0 + 64, Ksm[cur ^ 1], Vsm[cur ^ 1], wv, lane);

        f32x4 sacc[4] = {};
#pragma unroll
        for (int ks = 0; ks < 2; ++ks) {
#pragma unroll
            for (int kc = 0; kc < 4; ++kc) {
                const int rk = kc * 16 + qi;
                const bf16x8 ak = *(const bf16x8*)((const char*)Ksm[cur] + rk * 128 +
                                                   ((ks * 64 + g * 16) ^ xsw));
                sacc[kc] = __builtin_amdgcn_mfma_f32_16x16x32_bf16(ak, qf[ks], sacc[kc], 0, 0, 0);
            }
        }

        float p[4][4];
        float mymax = -1e30f;
        if (kt == ntile - 1) {
#pragma unroll
            for (int kc = 0; kc < 4; ++kc) {
#pragma unroll
                for (int r = 0; r < 4; ++r) {
                    const int key = key0 + kc * 16 + g * 4 + r;
                    float sv = sacc[kc][r];
                    if (key > qg) sv = -__builtin_inff();
                    p[kc][r] = sv;
                    mymax = fmaxf(mymax, sv);
                }
            }
        } else {
#pragma unroll
            for (int kc = 0; kc < 4; ++kc) {
#pragma unroll
                for (int r = 0; r < 4; ++r) {
                    p[kc][r] = sacc[kc][r];
                    mymax = fmaxf(mymax, sacc[kc][r]);
                }
            }
        }
        mymax = fmaxf(mymax, __shfl_xor(mymax, 16));
        mymax = fmaxf(mymax, __shfl_xor(mymax, 32));
        const float m_new = fmaxf(m_run, mymax);
        const float alpha = __expf(m_run - m_new);
        float lsum = 0.0f;
#pragma unroll
        for (int kc = 0; kc < 4; ++kc) {
#pragma unroll
            for (int r = 0; r < 4; ++r) {
                const float e = __expf(p[kc][r] - m_new);
                p[kc][r] = e;
                lsum += e;
            }
        }
        lsum += __shfl_xor(lsum, 16);
        lsum += __shfl_xor(lsum, 32);
        l_run = l_run * alpha + lsum;
        m_run = m_new;
#pragma unroll
        for (int c = 0; c < 4; ++c) {
#pragma unroll
            for (int r = 0; r < 4; ++r) oacc[c][r] *= alpha;
        }
#pragma unroll
        for (int kc = 0; kc < 4; ++kc) {
            u16x4 pk;
#pragma unroll
            for (int r = 0; r < 4; ++r) pk[r] = f2bf(p[kc][r]);
            *(u16x4*)(&Pl[wv][qi][kc * 16 + g * 4]) = pk;
        }
        bf16x8 pb[2];
#pragma unroll
        for (int ks = 0; ks < 2; ++ks)
            pb[ks] = *(const bf16x8*)(&Pl[wv][qi][ks * 32 + g * 8]);
#pragma unroll
        for (int ks = 0; ks < 2; ++ks) {
#pragma unroll
            for (int c = 0; c < 4; ++c) {
                const int rv = c * 16 + qi;
                const bf16x8 av = *(const bf16x8*)((const char*)Vsm[cur] + rv * 128 +
                                                   ((ks * 64 + g * 16) ^ xsw));
                oacc[c] = __builtin_amdgcn_mfma_f32_16x16x32_bf16(av, pb[ks], oacc[c], 0, 0, 0);
            }
        }
        __syncthreads();
        cur ^= 1;
    }

    const float inv = 1.0f / l_run;
#pragma unroll
    for (int c = 0; c < 4; ++c) {
        u16x4 o;
#pragma unroll
        for (int r = 0; r < 4; ++r) o[r] = f2bf(oacc[c][r] * inv);
        *(u16x4*)(&Y[((size_t)(b_ * 2048 + qg)) * 1024 + hh * 64 + c * 16 + g * 4]) = o;
    }
}

// ---------------- host ----------------
extern "C" void kernel_launch(void* const* d_in, const int* in_sizes, int n_in,
                              void* d_out, int out_size, void* d_ws, size_t ws_size,
                              hipStream_t stream) {
    (void)in_sizes; (void)n_in; (void)out_size;
    const float* x      = (const float*)d_in[0];
    const float* w_qkv  = (const float*)d_in[2];
    const float* b_qkv  = (const float*)d_in[3];
    const float* w_proj = (const float*)d_in[4];
    const float* b_proj = (const float*)d_in[5];
    const float* w_fc1  = (const float*)d_in[6];
    const float* b_fc1  = (const float*)d_in[7];
    const float* w_fc2  = (const float*)d_in[8];
    const float* b_fc2  = (const float*)d_in[9];
    const float* g1     = (const float*)d_in[10];
    const float* be1    = (const float*)d_in[11];
    const float* g2     = (const float*)d_in[12];
    const float* be2    = (const float*)d_in[13];

    char* ws = (char*)d_ws;
    size_t off = 0;
    auto alloc = [&](size_t bytes) { size_t r = off; off += (bytes + 255) & ~(size_t)255; return r; };
    u16*   wt_qkv = (u16*)(ws + alloc((size_t)3072 * 1024 * 2));
    u16*   wt_prj = (u16*)(ws + alloc((size_t)1024 * 1024 * 2));
    u16*   wt_fc1 = (u16*)(ws + alloc((size_t)4096 * 1024 * 2));
    u16*   wt_fc2 = (u16*)(ws + alloc((size_t)1024 * 4096 * 2));
    u16*   hbuf   = (u16*)(ws + alloc((size_t)4096 * 1024 * 2));
    float* x1     = (float*)(ws + alloc((size_t)4096 * 1024 * 4));
    char*  big    = ws + alloc((size_t)33554432);
    u16* qb  = (u16*)(big);
    u16* kb  = (u16*)(big + 8388608);
    u16* vtb = (u16*)(big + 16777216);
    u16* yb  = (u16*)(big + 25165824);
    u16* act = (u16*)(big);
    if (off > ws_size) return;
    const size_t part_need = (size_t)4 * 4096 * 1024 * 4;
    const bool has_part = (ws_size - off) >= part_need;
    float* part = (float*)(ws + off);

    const dim3 blk(256);
    tcvt_kernel<<<dim3(32, 96), blk, 0, stream>>>(w_qkv, wt_qkv, 1024, 3072);
    tcvt_kernel<<<dim3(32, 32), blk, 0, stream>>>(w_proj, wt_prj, 1024, 1024);
    tcvt_kernel<<<dim3(32, 128), blk, 0, stream>>>(w_fc1, wt_fc1, 1024, 4096);
    tcvt_kernel<<<dim3(128, 32), blk, 0, stream>>>(w_fc2, wt_fc2, 4096, 1024);

    ln_kernel<<<dim3(4096), blk, 0, stream>>>(x, g1, be1, hbuf);
    // QKV: 2-phase 256^2, grid 16*12=192
    gemm2p<0, 1><<<dim3(192), dim3(512), 0, stream>>>(hbuf, wt_qkv, b_qkv,
                                                      qb, kb, vtb, 4096, 3072, 1024);
    attn_kernel<<<dim3(32, 32), blk, 0, stream>>>(qb, kb, vtb, yb);
    // proj + residual (old path)
    gemm_bf16<64, 128, 1><<<dim3(8, 64), blk, 0, stream>>>(yb, wt_prj, b_proj, x,
                                                           x1, 4096, 1024, 1024);
    ln_kernel<<<dim3(4096), blk, 0, stream>>>(x1, g2, be2, hbuf);
    // FC1 + GELU: 2-phase, grid 256
    gemm2p<2, 1><<<dim3(256), dim3(512), 0, stream>>>(hbuf, wt_fc1, b_fc1,
                                                      act, nullptr, nullptr, 4096, 4096, 1024);
    if (has_part) {
        // FC2 split-K=4: grid 16*4*4=256, then fused reduce+bias+residual
        gemm2p<4, 4><<<dim3(256), dim3(512), 0, stream>>>(act, wt_fc2, nullptr,
                                                          part, nullptr, nullptr, 4096, 1024, 4096);
        reduce4_kernel<<<dim3(4096), blk, 0, stream>>>(part, b_fc2, x1, (float*)d_out);
    } else {
        gemm_bf16<64, 128, 3><<<dim3(8, 64), blk, 0, stream>>>(act, wt_fc2, b_fc2, x1,
                                                               (float*)d_out, 4096, 1024, 4096);
    }
}

// Round 5
// 291.275 us; speedup vs baseline: 1.1817x; 1.1674x over previous
//
#include <hip/hip_runtime.h>
#include <hip/hip_bf16.h>
#include <stdint.h>

typedef unsigned short u16;
typedef __attribute__((ext_vector_type(8))) short bf16x8;
typedef __attribute__((ext_vector_type(4))) float f32x4;
typedef __attribute__((ext_vector_type(4))) unsigned short u16x4;

#define DEVI static __device__ __forceinline__

DEVI u16 f2bf(float f) {
    unsigned int u = __builtin_bit_cast(unsigned int, f);
    return (u16)((u + 0x7fffu + ((u >> 16) & 1u)) >> 16);
}

DEVI void async_copy16(const void* g, void* l) {
    __builtin_amdgcn_global_load_lds((const __attribute__((address_space(1))) void*)g,
                                     (__attribute__((address_space(3))) void*)l,
                                     16, 0, 0);
}

// ---------------- weight transpose + f32->bf16 convert: src[K][N] -> dst[N][K] ----------------
__global__ __launch_bounds__(256) void tcvt_kernel(const float* __restrict__ src,
                                                   u16* __restrict__ dst,
                                                   int K, int N) {
    __shared__ float tile[32][33];
    const int k0 = blockIdx.x * 32, n0 = blockIdx.y * 32;
    const int t = threadIdx.x;
    const int c = t & 31, r0 = t >> 5;
#pragma unroll
    for (int p = 0; p < 4; ++p) {
        const int r = r0 + p * 8;
        tile[r][c] = src[(size_t)(k0 + r) * N + n0 + c];
    }
    __syncthreads();
#pragma unroll
    for (int p = 0; p < 4; ++p) {
        const int r = r0 + p * 8;
        dst[(size_t)(n0 + r) * K + k0 + c] = f2bf(tile[c][r]);
    }
}

// ---------------- LayerNorm (f32 in) -> bf16 out ----------------
__global__ __launch_bounds__(256) void ln_kernel(const float* __restrict__ x,
                                                 const float* __restrict__ gw,
                                                 const float* __restrict__ bw,
                                                 u16* __restrict__ out) {
    const int row = blockIdx.x;
    const int t = threadIdx.x;
    const float4 v = ((const float4*)(x + (size_t)row * 1024))[t];
    float s  = v.x + v.y + v.z + v.w;
    float ss = v.x * v.x + v.y * v.y + v.z * v.z + v.w * v.w;
#pragma unroll
    for (int off = 32; off > 0; off >>= 1) {
        s  += __shfl_down(s, off);
        ss += __shfl_down(ss, off);
    }
    __shared__ float red[8];
    const int wv = t >> 6;
    if ((t & 63) == 0) { red[wv] = s; red[4 + wv] = ss; }
    __syncthreads();
    if (t == 0) {
        red[0] = red[0] + red[1] + red[2] + red[3];
        red[4] = red[4] + red[5] + red[6] + red[7];
    }
    __syncthreads();
    const float mean = red[0] * (1.0f / 1024.0f);
    const float var  = red[4] * (1.0f / 1024.0f) - mean * mean;
    const float rstd = rsqrtf(var + 1e-5f);
    const float4 gv = ((const float4*)gw)[t];
    const float4 bv = ((const float4*)bw)[t];
    u16x4 o;
    o[0] = f2bf((v.x - mean) * rstd * gv.x + bv.x);
    o[1] = f2bf((v.y - mean) * rstd * gv.y + bv.y);
    o[2] = f2bf((v.z - mean) * rstd * gv.z + bv.z);
    o[3] = f2bf((v.w - mean) * rstd * gv.w + bv.w);
    ((u16x4*)out)[(size_t)row * 256 + t] = o;
}

// ================= 128x128 dbuf GEMM, 4 waves, BK=32, 4 distinct LDS arrays =================
// A [M][K] bf16 x Bt [N][K] bf16. Tile = 8 subtiles of [16 rows][32 cols] (1 KiB each),
// st_16x32 XOR swizzle applied via pre-swizzled global source (rule 21) + swizzled read
// offset — addressing HW-verified in rounds 3/4 (correct, 0 bank-conflict cycles).
// Distinct __shared__ arrays per buffer so alias analysis doesn't force vmcnt drains
// between prefetch (writes nxt) and ds_read (reads cur). One vmcnt(0)+barrier per tile.
// EPI 0: QKV scatter. EPI 2: gelu->bf16. EPI 4: f32 partial (split-K).
DEVI void stage32(const char* g, size_t ldb, char* lds0, int lane, int wv) {
    const int colsw = ((lane & 3) << 4) ^ (lane & 32);  // inverse-swizzled source col bytes
    const int rl = lane >> 2;
#pragma unroll
    for (int i = 0; i < 2; ++i) {
        const int c = wv * 2 + i;   // subtile 0..7
        async_copy16(g + (size_t)(c * 16 + rl) * ldb + colsw, lds0 + c * 1024);
    }
}

template <int EPI, int SPLITK>
__global__ __launch_bounds__(256, 4) void gemmv5(const u16* __restrict__ A,
                                                 const u16* __restrict__ Bt,
                                                 const float* __restrict__ bias,
                                                 void* __restrict__ out0,
                                                 void* __restrict__ out1,
                                                 void* __restrict__ out2,
                                                 int M, int N, int K) {
    __shared__ __align__(16) char As0[8192];
    __shared__ __align__(16) char As1[8192];
    __shared__ __align__(16) char Bs0[8192];
    __shared__ __align__(16) char Bs1[8192];
    const int tid = threadIdx.x;
    const int lane = tid & 63, wv = tid >> 6;
    const int wr = wv >> 1, wc = wv & 1;        // 2M x 2N waves, 64x64 each
    const int g = lane >> 4, qq = lane & 15;
    const int rdoff = qq * 64 + ((g * 16) ^ ((qq & 8) << 2));  // swizzled read offset

    // XCD-aware bijective swizzle (all grids used are multiples of 8)
    const int nwg = gridDim.x;
    int id = blockIdx.x;
    id = (id & 7) * (nwg >> 3) + (id >> 3);
    const int MT = M >> 7, NTn = N >> 7;
    const int slice = id / (MT * NTn);
    const int r2 = id % (MT * NTn);
    const int m0 = (r2 % MT) << 7;
    const int n0 = (r2 / MT) << 7;
    const int Ks = K / SPLITK;
    const int NT = Ks >> 5;                      // 32-wide K tiles (NT is even: 16 or 32)
    const size_t ldb = (size_t)K * 2;

    const char* pa = (const char*)A + (size_t)m0 * ldb + (size_t)slice * Ks * 2;
    const char* pb = (const char*)Bt + (size_t)n0 * ldb + (size_t)slice * Ks * 2;

    f32x4 acc[4][4] = {};

    auto compute = [&](const char* bufA, const char* bufB) {
        bf16x8 fa[4], fb[4];
#pragma unroll
        for (int fn = 0; fn < 4; ++fn)
            fb[fn] = *(const bf16x8*)(bufB + (wc * 4 + fn) * 1024 + rdoff);
#pragma unroll
        for (int fm = 0; fm < 4; ++fm)
            fa[fm] = *(const bf16x8*)(bufA + (wr * 4 + fm) * 1024 + rdoff);
        asm volatile("s_waitcnt lgkmcnt(0)" ::: "memory");
        __builtin_amdgcn_sched_barrier(0);
        __builtin_amdgcn_s_setprio(1);
#pragma unroll
        for (int fm = 0; fm < 4; ++fm)
#pragma unroll
            for (int fn = 0; fn < 4; ++fn)
                acc[fm][fn] = __builtin_amdgcn_mfma_f32_16x16x32_bf16(fa[fm], fb[fn],
                                                                      acc[fm][fn], 0, 0, 0);
        __builtin_amdgcn_s_setprio(0);
    };

    // prologue: tile 0 -> buf0
    stage32(pa, ldb, As0, lane, wv);
    stage32(pb, ldb, Bs0, lane, wv);
    asm volatile("s_waitcnt vmcnt(0)" ::: "memory");
    __builtin_amdgcn_s_barrier();

    for (int t = 0; t < NT; t += 2) {
        // even tile: compute buf0, prefetch t+1 -> buf1
        if (t + 1 < NT) {
            stage32(pa + (size_t)(t + 1) * 64, ldb, As1, lane, wv);
            stage32(pb + (size_t)(t + 1) * 64, ldb, Bs1, lane, wv);
        }
        compute(As0, Bs0);
        asm volatile("s_waitcnt vmcnt(0)" ::: "memory");
        __builtin_amdgcn_s_barrier();
        // odd tile: compute buf1, prefetch t+2 -> buf0
        if (t + 2 < NT) {
            stage32(pa + (size_t)(t + 2) * 64, ldb, As0, lane, wv);
            stage32(pb + (size_t)(t + 2) * 64, ldb, Bs0, lane, wv);
        }
        compute(As1, Bs1);
        asm volatile("s_waitcnt vmcnt(0)" ::: "memory");
        __builtin_amdgcn_s_barrier();
    }

    // epilogue: lane holds D[g*4+r][qq] per 16x16 fragment
#pragma unroll
    for (int fm = 0; fm < 4; ++fm) {
#pragma unroll
        for (int fn = 0; fn < 4; ++fn) {
            const int mrow = m0 + wr * 64 + fm * 16 + g * 4;
            const int ncol = n0 + wc * 64 + fn * 16 + qq;
            if constexpr (EPI == 0) {
                const float bs = bias[ncol];
                const int sec = ncol >> 10;
                const int hd_ = ncol & 1023;
                const int hh = hd_ >> 6, dd = hd_ & 63;
                if (sec == 2) {
                    const int b_ = mrow >> 11, l_ = mrow & 2047;
                    u16x4 pk;
#pragma unroll
                    for (int r = 0; r < 4; ++r) pk[r] = f2bf(acc[fm][fn][r] + bs);
                    *(u16x4*)((u16*)out2 + ((size_t)((b_ * 16 + hh) * 64 + dd)) * 2048 + l_) = pk;
                } else {
                    u16* dst = (sec == 0) ? (u16*)out0 : (u16*)out1;
                    const float sc = (sec == 0) ? 0.125f : 1.0f;
#pragma unroll
                    for (int r = 0; r < 4; ++r) {
                        const int mr = mrow + r;
                        const int b_ = mr >> 11, l_ = mr & 2047;
                        dst[((size_t)((b_ * 16 + hh) * 2048 + l_)) * 64 + dd] =
                            f2bf((acc[fm][fn][r] + bs) * sc);
                    }
                }
            } else if constexpr (EPI == 2) {
                const float bs = bias[ncol];
                u16* dst = (u16*)out0;
#pragma unroll
                for (int r = 0; r < 4; ++r) {
                    float v = acc[fm][fn][r] + bs;
                    v = 0.5f * v * (1.0f + erff(v * 0.70710678118f));
                    dst[(size_t)(mrow + r) * N + ncol] = f2bf(v);
                }
            } else {  // EPI 4: raw f32 partial for split-K
                float* dst = (float*)out0 + (size_t)slice * M * N;
#pragma unroll
                for (int r = 0; r < 4; ++r)
                    dst[(size_t)(mrow + r) * N + ncol] = acc[fm][fn][r];
            }
        }
    }
}

// split-K reduce + bias + residual -> f32 out
template <int SPLIT>
__global__ __launch_bounds__(256) void reduceN_kernel(const float* __restrict__ p,
                                                      const float* __restrict__ bias,
                                                      const float* __restrict__ res,
                                                      float* __restrict__ out,
                                                      int MN4, int N4) {
    const int i = blockIdx.x * 256 + threadIdx.x;   // one float4
    float4 s = ((const float4*)p)[i];
#pragma unroll
    for (int s2 = 1; s2 < SPLIT; ++s2) {
        const float4 q = ((const float4*)p)[(size_t)s2 * MN4 + i];
        s.x += q.x; s.y += q.y; s.z += q.z; s.w += q.w;
    }
    const float4 r = ((const float4*)res)[i];
    const float4 bs = ((const float4*)bias)[i & (N4 - 1)];
    float4 o;
    o.x = s.x + r.x + bs.x;
    o.y = s.y + r.y + bs.y;
    o.z = s.z + r.z + bs.z;
    o.w = s.w + r.w + bs.w;
    ((float4*)out)[i] = o;
}

// ---------------- old 2-phase 128-class GEMM (fallback only, EPI: f32 val+bias+res) ---------
template <int BM, int BN>
__global__ __launch_bounds__(256, 2) void gemm_bf16(const u16* __restrict__ A,
                                                    const u16* __restrict__ Bt,
                                                    const float* __restrict__ bias,
                                                    const float* __restrict__ res,
                                                    void* __restrict__ out0,
                                                    int M, int N, int K) {
    constexpr int WM = BM / 2, WN = BN / 2;
    constexpr int FM = WM / 16, FN = WN / 16;
    __shared__ __align__(16) short Asm[BM * 32];
    __shared__ __align__(16) short Bsm[BN * 32];
    const int tid = threadIdx.x;
    const int lane = tid & 63, wv = tid >> 6;
    const int wr = wv >> 1, wc = wv & 1;
    const int g = lane >> 4, qq = lane & 15;
    const int n0 = blockIdx.x * BN, m0 = blockIdx.y * BM;

    f32x4 acc[FM][FN] = {};
    const char* srcA = (const char*)A + ((size_t)m0 * K) * 2;
    const char* srcB = (const char*)Bt + ((size_t)n0 * K) * 2;
    const size_t strideAB = (size_t)K * 2;

    for (int k0 = 0; k0 < K; k0 += 32) {
#pragma unroll
        for (int i = 0; i < BM * 64 / 4096; ++i) {
            const int b = i * 4096 + wv * 1024 + lane * 16;
            const int row = b >> 6, colb = b & 63;
            async_copy16(srcA + (size_t)row * strideAB + (size_t)k0 * 2 + colb,
                         (char*)Asm + i * 4096 + wv * 1024);
        }
#pragma unroll
        for (int i = 0; i < BN * 64 / 4096; ++i) {
            const int b = i * 4096 + wv * 1024 + lane * 16;
            const int row = b >> 6, colb = b & 63;
            async_copy16(srcB + (size_t)row * strideAB + (size_t)k0 * 2 + colb,
                         (char*)Bsm + i * 4096 + wv * 1024);
        }
        __syncthreads();
        bf16x8 af[FM], bfr[FN];
#pragma unroll
        for (int fm = 0; fm < FM; ++fm)
            af[fm] = *(const bf16x8*)(&Asm[(wr * WM + fm * 16 + qq) * 32 + g * 8]);
#pragma unroll
        for (int fn = 0; fn < FN; ++fn)
            bfr[fn] = *(const bf16x8*)(&Bsm[(wc * WN + fn * 16 + qq) * 32 + g * 8]);
#pragma unroll
        for (int fm = 0; fm < FM; ++fm)
#pragma unroll
            for (int fn = 0; fn < FN; ++fn)
                acc[fm][fn] = __builtin_amdgcn_mfma_f32_16x16x32_bf16(af[fm], bfr[fn],
                                                                      acc[fm][fn], 0, 0, 0);
        __syncthreads();
    }

    const int g4 = g * 4;
#pragma unroll
    for (int fm = 0; fm < FM; ++fm) {
#pragma unroll
        for (int fn = 0; fn < FN; ++fn) {
            const int mrow = m0 + wr * WM + fm * 16 + g4;
            const int ncol = n0 + wc * WN + fn * 16 + qq;
            const float bs = bias[ncol];
            float* dst = (float*)out0;
#pragma unroll
            for (int r = 0; r < 4; ++r) {
                const int mr = mrow + r;
                dst[(size_t)mr * N + ncol] = acc[fm][fn][r] + bs + res[(size_t)mr * N + ncol];
            }
        }
    }
}

// ---------------- causal flash attention (LDS-staged, double-buffered K/V) ----------------
DEVI void stage_kv(const char* kbase, const char* vbase, int key0,
                   u16* ksm, u16* vsm, int wv, int lane) {
#pragma unroll
    for (int i = 0; i < 2; ++i) {
        const int c = wv + i * 4;
        const int off = c * 1024 + lane * 16;
        const int row = off >> 7;
        const int scol = (off & 127) ^ ((row & 7) << 4);
        async_copy16(kbase + (size_t)key0 * 128 + (size_t)row * 128 + scol,
                     (char*)ksm + c * 1024);
    }
#pragma unroll
    for (int i = 0; i < 2; ++i) {
        const int c = wv + i * 4;
        const int row = c * 8 + (lane >> 3);
        const int scol = ((lane & 7) * 16) ^ ((row & 7) << 4);
        async_copy16(vbase + (size_t)row * 4096 + (size_t)key0 * 2 + scol,
                     (char*)vsm + c * 1024);
    }
}

__global__ __launch_bounds__(256, 3) void attn_kernel(const u16* __restrict__ Q,
                                                      const u16* __restrict__ Kk,
                                                      const u16* __restrict__ Vt,
                                                      u16* __restrict__ Y) {
    const int bh = blockIdx.y;
    const int b_ = bh >> 4, hh = bh & 15;
    const int qb = gridDim.x - 1 - blockIdx.x;
    const int tid = threadIdx.x;
    const int wv = tid >> 6, lane = tid & 63;
    const int g = lane >> 4, qi = lane & 15;
    const int xsw = (qi & 7) << 4;
    const int q0 = qb * 64 + wv * 16;
    const int qg = q0 + qi;

    __shared__ __align__(16) u16 Ksm[2][4096];
    __shared__ __align__(16) u16 Vsm[2][4096];
    __shared__ __align__(16) u16 Pl[4][16][72];

    const u16*  Qb = Q + ((size_t)bh * 2048 + q0) * 64;
    const char* Kb = (const char*)(Kk + (size_t)bh * 2048 * 64);
    const char* Vb = (const char*)(Vt + (size_t)bh * 64 * 2048);

    bf16x8 qf[2];
#pragma unroll
    for (int ks = 0; ks < 2; ++ks)
        qf[ks] = *(const bf16x8*)(Qb + qi * 64 + ks * 32 + g * 8);

    f32x4 oacc[4] = {};
    float m_run = -1e30f, l_run = 0.0f;
    const int ntile = qb + 1;

    stage_kv(Kb, Vb, 0, Ksm[0], Vsm[0], wv, lane);
    __syncthreads();

    int cur = 0;
    for (int kt = 0; kt < ntile; ++kt) {
        const int key0 = kt * 64;
        if (kt + 1 < ntile)
            stage_kv(Kb, Vb, key0 + 64, Ksm[cur ^ 1], Vsm[cur ^ 1], wv, lane);

        f32x4 sacc[4] = {};
#pragma unroll
        for (int ks = 0; ks < 2; ++ks) {
#pragma unroll
            for (int kc = 0; kc < 4; ++kc) {
                const int rk = kc * 16 + qi;
                const bf16x8 ak = *(const bf16x8*)((const char*)Ksm[cur] + rk * 128 +
                                                   ((ks * 64 + g * 16) ^ xsw));
                sacc[kc] = __builtin_amdgcn_mfma_f32_16x16x32_bf16(ak, qf[ks], sacc[kc], 0, 0, 0);
            }
        }

        float p[4][4];
        float mymax = -1e30f;
        if (kt == ntile - 1) {
#pragma unroll
            for (int kc = 0; kc < 4; ++kc) {
#pragma unroll
                for (int r = 0; r < 4; ++r) {
                    const int key = key0 + kc * 16 + g * 4 + r;
                    float sv = sacc[kc][r];
                    if (key > qg) sv = -__builtin_inff();
                    p[kc][r] = sv;
                    mymax = fmaxf(mymax, sv);
                }
            }
        } else {
#pragma unroll
            for (int kc = 0; kc < 4; ++kc) {
#pragma unroll
                for (int r = 0; r < 4; ++r) {
                    p[kc][r] = sacc[kc][r];
                    mymax = fmaxf(mymax, sacc[kc][r]);
                }
            }
        }
        mymax = fmaxf(mymax, __shfl_xor(mymax, 16));
        mymax = fmaxf(mymax, __shfl_xor(mymax, 32));
        const float m_new = fmaxf(m_run, mymax);
        const float alpha = __expf(m_run - m_new);
        float lsum = 0.0f;
#pragma unroll
        for (int kc = 0; kc < 4; ++kc) {
#pragma unroll
            for (int r = 0; r < 4; ++r) {
                const float e = __expf(p[kc][r] - m_new);
                p[kc][r] = e;
                lsum += e;
            }
        }
        lsum += __shfl_xor(lsum, 16);
        lsum += __shfl_xor(lsum, 32);
        l_run = l_run * alpha + lsum;
        m_run = m_new;
#pragma unroll
        for (int c = 0; c < 4; ++c) {
#pragma unroll
            for (int r = 0; r < 4; ++r) oacc[c][r] *= alpha;
        }
#pragma unroll
        for (int kc = 0; kc < 4; ++kc) {
            u16x4 pk;
#pragma unroll
            for (int r = 0; r < 4; ++r) pk[r] = f2bf(p[kc][r]);
            *(u16x4*)(&Pl[wv][qi][kc * 16 + g * 4]) = pk;
        }
        bf16x8 pb[2];
#pragma unroll
        for (int ks = 0; ks < 2; ++ks)
            pb[ks] = *(const bf16x8*)(&Pl[wv][qi][ks * 32 + g * 8]);
#pragma unroll
        for (int ks = 0; ks < 2; ++ks) {
#pragma unroll
            for (int c = 0; c < 4; ++c) {
                const int rv = c * 16 + qi;
                const bf16x8 av = *(const bf16x8*)((const char*)Vsm[cur] + rv * 128 +
                                                   ((ks * 64 + g * 16) ^ xsw));
                oacc[c] = __builtin_amdgcn_mfma_f32_16x16x32_bf16(av, pb[ks], oacc[c], 0, 0, 0);
            }
        }
        __syncthreads();
        cur ^= 1;
    }

    const float inv = 1.0f / l_run;
#pragma unroll
    for (int c = 0; c < 4; ++c) {
        u16x4 o;
#pragma unroll
        for (int r = 0; r < 4; ++r) o[r] = f2bf(oacc[c][r] * inv);
        *(u16x4*)(&Y[((size_t)(b_ * 2048 + qg)) * 1024 + hh * 64 + c * 16 + g * 4]) = o;
    }
}

// ---------------- host ----------------
extern "C" void kernel_launch(void* const* d_in, const int* in_sizes, int n_in,
                              void* d_out, int out_size, void* d_ws, size_t ws_size,
                              hipStream_t stream) {
    (void)in_sizes; (void)n_in; (void)out_size;
    const float* x      = (const float*)d_in[0];
    const float* w_qkv  = (const float*)d_in[2];
    const float* b_qkv  = (const float*)d_in[3];
    const float* w_proj = (const float*)d_in[4];
    const float* b_proj = (const float*)d_in[5];
    const float* w_fc1  = (const float*)d_in[6];
    const float* b_fc1  = (const float*)d_in[7];
    const float* w_fc2  = (const float*)d_in[8];
    const float* b_fc2  = (const float*)d_in[9];
    const float* g1     = (const float*)d_in[10];
    const float* be1    = (const float*)d_in[11];
    const float* g2     = (const float*)d_in[12];
    const float* be2    = (const float*)d_in[13];

    char* ws = (char*)d_ws;
    size_t off = 0;
    auto alloc = [&](size_t bytes) { size_t r = off; off += (bytes + 255) & ~(size_t)255; return r; };
    u16*   wt_qkv = (u16*)(ws + alloc((size_t)3072 * 1024 * 2));
    u16*   wt_prj = (u16*)(ws + alloc((size_t)1024 * 1024 * 2));
    u16*   wt_fc1 = (u16*)(ws + alloc((size_t)4096 * 1024 * 2));
    u16*   wt_fc2 = (u16*)(ws + alloc((size_t)1024 * 4096 * 2));
    u16*   hbuf   = (u16*)(ws + alloc((size_t)4096 * 1024 * 2));
    float* x1     = (float*)(ws + alloc((size_t)4096 * 1024 * 4));
    char*  big    = ws + alloc((size_t)33554432);
    u16* qb  = (u16*)(big);
    u16* kb  = (u16*)(big + 8388608);
    u16* vtb = (u16*)(big + 16777216);
    u16* yb  = (u16*)(big + 25165824);
    u16* act = (u16*)(big);
    if (off > ws_size) return;
    const size_t part_need = (size_t)4 * 4096 * 1024 * 4;   // covers splitK=4 (FC2) and =2 (proj)
    const bool has_part = (ws_size - off) >= part_need;
    float* part = (float*)(ws + off);

    const dim3 blk(256);
    tcvt_kernel<<<dim3(32, 96), blk, 0, stream>>>(w_qkv, wt_qkv, 1024, 3072);
    tcvt_kernel<<<dim3(32, 32), blk, 0, stream>>>(w_proj, wt_prj, 1024, 1024);
    tcvt_kernel<<<dim3(32, 128), blk, 0, stream>>>(w_fc1, wt_fc1, 1024, 4096);
    tcvt_kernel<<<dim3(128, 32), blk, 0, stream>>>(w_fc2, wt_fc2, 4096, 1024);

    ln_kernel<<<dim3(4096), blk, 0, stream>>>(x, g1, be1, hbuf);
    // QKV: 128^2 dbuf, grid 32*24 = 768
    gemmv5<0, 1><<<dim3(768), blk, 0, stream>>>(hbuf, wt_qkv, b_qkv,
                                                qb, kb, vtb, 4096, 3072, 1024);
    attn_kernel<<<dim3(32, 32), blk, 0, stream>>>(qb, kb, vtb, yb);
    if (has_part) {
        // proj split-K=2: grid 32*8*2 = 512, then reduce(+bias+x) -> x1
        gemmv5<4, 2><<<dim3(512), blk, 0, stream>>>(yb, wt_prj, nullptr,
                                                    part, nullptr, nullptr, 4096, 1024, 1024);
        reduceN_kernel<2><<<dim3(4096), blk, 0, stream>>>(part, b_proj, x, x1, 1048576, 256);
    } else {
        gemm_bf16<64, 128><<<dim3(8, 64), blk, 0, stream>>>(yb, wt_prj, b_proj, x,
                                                            x1, 4096, 1024, 1024);
    }
    ln_kernel<<<dim3(4096), blk, 0, stream>>>(x1, g2, be2, hbuf);
    // FC1 + GELU: grid 32*32 = 1024
    gemmv5<2, 1><<<dim3(1024), blk, 0, stream>>>(hbuf, wt_fc1, b_fc1,
                                                 act, nullptr, nullptr, 4096, 4096, 1024);
    if (has_part) {
        // FC2 split-K=4: grid 32*8*4 = 1024, then reduce(+bias+x1) -> d_out
        gemmv5<4, 4><<<dim3(1024), blk, 0, stream>>>(act, wt_fc2, nullptr,
                                                     part, nullptr, nullptr, 4096, 1024, 4096);
        reduceN_kernel<4><<<dim3(4096), blk, 0, stream>>>(part, b_fc2, x1, (float*)d_out,
                                                          1048576, 256);
    } else {
        gemm_bf16<64, 128><<<dim3(8, 64), blk, 0, stream>>>(act, wt_fc2, b_fc2, x1,
                                                            (float*)d_out, 4096, 1024, 4096);
    }
}

// Round 6
// 270.464 us; speedup vs baseline: 1.2726x; 1.0769x over previous
//
#include <hip/hip_runtime.h>
#include <hip/hip_bf16.h>
#include <stdint.h>

typedef unsigned short u16;
typedef __attribute__((ext_vector_type(8))) short bf16x8;
typedef __attribute__((ext_vector_type(4))) float f32x4;
typedef __attribute__((ext_vector_type(4))) unsigned short u16x4;

#define DEVI static __device__ __forceinline__

DEVI u16 f2bf(float f) {
    unsigned int u = __builtin_bit_cast(unsigned int, f);
    return (u16)((u + 0x7fffu + ((u >> 16) & 1u)) >> 16);
}

DEVI float gelu_f(float v) {
    // tanh-form GELU: x * sigmoid(1.5957691(x + 0.044715 x^3)); |err vs exact| <= ~3e-4
    const float z = 1.5957691216f * (v + 0.044715f * v * v * v);
    return v / (1.0f + __expf(-z));
}

DEVI void async_copy16(const void* g, void* l) {
    __builtin_amdgcn_global_load_lds((const __attribute__((address_space(1))) void*)g,
                                     (__attribute__((address_space(3))) void*)l,
                                     16, 0, 0);
}

// ---------------- weight transpose + f32->bf16 convert: src[K][N] -> dst[N][K] ----------------
__global__ __launch_bounds__(256) void tcvt_kernel(const float* __restrict__ src,
                                                   u16* __restrict__ dst,
                                                   int K, int N) {
    __shared__ float tile[32][33];
    const int k0 = blockIdx.x * 32, n0 = blockIdx.y * 32;
    const int t = threadIdx.x;
    const int c = t & 31, r0 = t >> 5;
#pragma unroll
    for (int p = 0; p < 4; ++p) {
        const int r = r0 + p * 8;
        tile[r][c] = src[(size_t)(k0 + r) * N + n0 + c];
    }
    __syncthreads();
#pragma unroll
    for (int p = 0; p < 4; ++p) {
        const int r = r0 + p * 8;
        dst[(size_t)(n0 + r) * K + k0 + c] = f2bf(tile[c][r]);
    }
}

// ---------------- LayerNorm (f32 in) -> bf16 out ----------------
__global__ __launch_bounds__(256) void ln_kernel(const float* __restrict__ x,
                                                 const float* __restrict__ gw,
                                                 const float* __restrict__ bw,
                                                 u16* __restrict__ out) {
    const int row = blockIdx.x;
    const int t = threadIdx.x;
    const float4 v = ((const float4*)(x + (size_t)row * 1024))[t];
    float s  = v.x + v.y + v.z + v.w;
    float ss = v.x * v.x + v.y * v.y + v.z * v.z + v.w * v.w;
#pragma unroll
    for (int off = 32; off > 0; off >>= 1) {
        s  += __shfl_down(s, off);
        ss += __shfl_down(ss, off);
    }
    __shared__ float red[8];
    const int wv = t >> 6;
    if ((t & 63) == 0) { red[wv] = s; red[4 + wv] = ss; }
    __syncthreads();
    if (t == 0) {
        red[0] = red[0] + red[1] + red[2] + red[3];
        red[4] = red[4] + red[5] + red[6] + red[7];
    }
    __syncthreads();
    const float mean = red[0] * (1.0f / 1024.0f);
    const float var  = red[4] * (1.0f / 1024.0f) - mean * mean;
    const float rstd = rsqrtf(var + 1e-5f);
    const float4 gv = ((const float4*)gw)[t];
    const float4 bv = ((const float4*)bw)[t];
    u16x4 o;
    o[0] = f2bf((v.x - mean) * rstd * gv.x + bv.x);
    o[1] = f2bf((v.y - mean) * rstd * gv.y + bv.y);
    o[2] = f2bf((v.z - mean) * rstd * gv.z + bv.z);
    o[3] = f2bf((v.w - mean) * rstd * gv.w + bv.w);
    ((u16x4*)out)[(size_t)row * 256 + t] = o;
}

// ================= 128x128 GEMM, BK=64, single-buffer, m97-pure schedule =================
// A [M][K] bf16 x Bt [N][K] bf16. 256 threads (4 waves, 2M x 2N of 64x64).
// LDS: As/Bs 16 KiB each = 16 slots [16 rows][64B], slot s = kh*8 + subtile.
// st_16x32 XOR swizzle via pre-swizzled global source (rule 21) + swizzled read offset
// (addressing HW-verified rounds 3-5: correct, 0 bank-conflict cycles).
// Schedule per tile: stage(t) -> __syncthreads -> compute kh0,kh1 -> __syncthreads.
// No prefetch, no inline-asm waits (all measured neutral); TLP across ~4 blocks/CU hides stalls.
DEVI void stage64(const char* g, size_t ldb, char* lds0, int lane, int wv) {
    const int colsw = ((lane & 3) << 4) ^ (lane & 32);  // inverse-swizzled source col bytes
    const int rl = lane >> 2;
#pragma unroll
    for (int i = 0; i < 4; ++i) {
        const int s = wv * 4 + i;            // slot 0..15
        const int kh = s >> 3, c = s & 7;    // k-half, 16-row subtile
        async_copy16(g + (size_t)(c * 16 + rl) * ldb + kh * 64 + colsw,
                     lds0 + s * 1024);
    }
}

// EPI 0: QKV scatter. EPI 2: gelu->bf16. EPI 4: f32 partial (split-K).
template <int EPI, int SPLITK>
__global__ __launch_bounds__(256, 4) void gemmv6(const u16* __restrict__ A,
                                                 const u16* __restrict__ Bt,
                                                 const float* __restrict__ bias,
                                                 void* __restrict__ out0,
                                                 void* __restrict__ out1,
                                                 void* __restrict__ out2,
                                                 int M, int N, int K) {
    __shared__ __align__(16) char As[16384];
    __shared__ __align__(16) char Bs[16384];
    const int tid = threadIdx.x;
    const int lane = tid & 63, wv = tid >> 6;
    const int wr = wv >> 1, wc = wv & 1;        // 2M x 2N waves, 64x64 each
    const int g = lane >> 4, qq = lane & 15;
    const int rdoff = qq * 64 + ((g * 16) ^ ((qq & 8) << 2));  // swizzled read offset

    // XCD-aware bijective swizzle (all grids used are multiples of 8)
    const int nwg = gridDim.x;
    int id = blockIdx.x;
    id = (id & 7) * (nwg >> 3) + (id >> 3);
    const int MT = M >> 7, NTn = N >> 7;
    const int slice = id / (MT * NTn);
    const int r2 = id % (MT * NTn);
    const int m0 = (r2 % MT) << 7;
    const int n0 = (r2 / MT) << 7;
    const int Ks = K / SPLITK;
    const int NT = Ks >> 6;                      // 64-wide K tiles
    const size_t ldb = (size_t)K * 2;

    const char* pa = (const char*)A + (size_t)m0 * ldb + (size_t)slice * Ks * 2;
    const char* pb = (const char*)Bt + (size_t)n0 * ldb + (size_t)slice * Ks * 2;

    f32x4 acc[4][4] = {};

    for (int t = 0; t < NT; ++t) {
        stage64(pa + (size_t)t * 128, ldb, As, lane, wv);
        stage64(pb + (size_t)t * 128, ldb, Bs, lane, wv);
        __syncthreads();
#pragma unroll
        for (int kh = 0; kh < 2; ++kh) {
            bf16x8 fa[4], fb[4];
#pragma unroll
            for (int fn = 0; fn < 4; ++fn)
                fb[fn] = *(const bf16x8*)(Bs + (kh * 8 + wc * 4 + fn) * 1024 + rdoff);
#pragma unroll
            for (int fm = 0; fm < 4; ++fm)
                fa[fm] = *(const bf16x8*)(As + (kh * 8 + wr * 4 + fm) * 1024 + rdoff);
#pragma unroll
            for (int fm = 0; fm < 4; ++fm)
#pragma unroll
                for (int fn = 0; fn < 4; ++fn)
                    acc[fm][fn] = __builtin_amdgcn_mfma_f32_16x16x32_bf16(fa[fm], fb[fn],
                                                                          acc[fm][fn], 0, 0, 0);
        }
        __syncthreads();
    }

    // epilogue: lane holds D[g*4+r][qq] per 16x16 fragment
#pragma unroll
    for (int fm = 0; fm < 4; ++fm) {
#pragma unroll
        for (int fn = 0; fn < 4; ++fn) {
            const int mrow = m0 + wr * 64 + fm * 16 + g * 4;
            const int ncol = n0 + wc * 64 + fn * 16 + qq;
            if constexpr (EPI == 0) {
                const float bs = bias[ncol];
                const int sec = ncol >> 10;
                const int hd_ = ncol & 1023;
                const int hh = hd_ >> 6, dd = hd_ & 63;
                if (sec == 2) {
                    const int b_ = mrow >> 11, l_ = mrow & 2047;
                    u16x4 pk;
#pragma unroll
                    for (int r = 0; r < 4; ++r) pk[r] = f2bf(acc[fm][fn][r] + bs);
                    *(u16x4*)((u16*)out2 + ((size_t)((b_ * 16 + hh) * 64 + dd)) * 2048 + l_) = pk;
                } else {
                    u16* dst = (sec == 0) ? (u16*)out0 : (u16*)out1;
                    const float sc = (sec == 0) ? 0.125f : 1.0f;
#pragma unroll
                    for (int r = 0; r < 4; ++r) {
                        const int mr = mrow + r;
                        const int b_ = mr >> 11, l_ = mr & 2047;
                        dst[((size_t)((b_ * 16 + hh) * 2048 + l_)) * 64 + dd] =
                            f2bf((acc[fm][fn][r] + bs) * sc);
                    }
                }
            } else if constexpr (EPI == 2) {
                const float bs = bias[ncol];
                u16* dst = (u16*)out0;
#pragma unroll
                for (int r = 0; r < 4; ++r)
                    dst[(size_t)(mrow + r) * N + ncol] = f2bf(gelu_f(acc[fm][fn][r] + bs));
            } else {  // EPI 4: raw f32 partial for split-K
                float* dst = (float*)out0 + (size_t)slice * M * N;
#pragma unroll
                for (int r = 0; r < 4; ++r)
                    dst[(size_t)(mrow + r) * N + ncol] = acc[fm][fn][r];
            }
        }
    }
}

// split-K reduce + bias + residual -> f32 out
template <int SPLIT>
__global__ __launch_bounds__(256) void reduceN_kernel(const float* __restrict__ p,
                                                      const float* __restrict__ bias,
                                                      const float* __restrict__ res,
                                                      float* __restrict__ out,
                                                      int MN4, int N4) {
    const int i = blockIdx.x * 256 + threadIdx.x;   // one float4
    float4 s = ((const float4*)p)[i];
#pragma unroll
    for (int s2 = 1; s2 < SPLIT; ++s2) {
        const float4 q = ((const float4*)p)[(size_t)s2 * MN4 + i];
        s.x += q.x; s.y += q.y; s.z += q.z; s.w += q.w;
    }
    const float4 r = ((const float4*)res)[i];
    const float4 bs = ((const float4*)bias)[i & (N4 - 1)];
    float4 o;
    o.x = s.x + r.x + bs.x;
    o.y = s.y + r.y + bs.y;
    o.z = s.z + r.z + bs.z;
    o.w = s.w + r.w + bs.w;
    ((float4*)out)[i] = o;
}

// ---------------- causal flash attention (LDS-staged, double-buffered K/V) ----------------
DEVI void stage_kv(const char* kbase, const char* vbase, int key0,
                   u16* ksm, u16* vsm, int wv, int lane) {
#pragma unroll
    for (int i = 0; i < 2; ++i) {
        const int c = wv + i * 4;
        const int off = c * 1024 + lane * 16;
        const int row = off >> 7;
        const int scol = (off & 127) ^ ((row & 7) << 4);
        async_copy16(kbase + (size_t)key0 * 128 + (size_t)row * 128 + scol,
                     (char*)ksm + c * 1024);
    }
#pragma unroll
    for (int i = 0; i < 2; ++i) {
        const int c = wv + i * 4;
        const int row = c * 8 + (lane >> 3);
        const int scol = ((lane & 7) * 16) ^ ((row & 7) << 4);
        async_copy16(vbase + (size_t)row * 4096 + (size_t)key0 * 2 + scol,
                     (char*)vsm + c * 1024);
    }
}

__global__ __launch_bounds__(256, 3) void attn_kernel(const u16* __restrict__ Q,
                                                      const u16* __restrict__ Kk,
                                                      const u16* __restrict__ Vt,
                                                      u16* __restrict__ Y) {
    const int bh = blockIdx.y;
    const int b_ = bh >> 4, hh = bh & 15;
    const int qb = gridDim.x - 1 - blockIdx.x;
    const int tid = threadIdx.x;
    const int wv = tid >> 6, lane = tid & 63;
    const int g = lane >> 4, qi = lane & 15;
    const int xsw = (qi & 7) << 4;
    const int q0 = qb * 64 + wv * 16;
    const int qg = q0 + qi;

    __shared__ __align__(16) u16 Ksm[2][4096];
    __shared__ __align__(16) u16 Vsm[2][4096];
    __shared__ __align__(16) u16 Pl[4][16][72];

    const u16*  Qb = Q + ((size_t)bh * 2048 + q0) * 64;
    const char* Kb = (const char*)(Kk + (size_t)bh * 2048 * 64);
    const char* Vb = (const char*)(Vt + (size_t)bh * 64 * 2048);

    bf16x8 qf[2];
#pragma unroll
    for (int ks = 0; ks < 2; ++ks)
        qf[ks] = *(const bf16x8*)(Qb + qi * 64 + ks * 32 + g * 8);

    f32x4 oacc[4] = {};
    float m_run = -1e30f, l_run = 0.0f;
    const int ntile = qb + 1;

    stage_kv(Kb, Vb, 0, Ksm[0], Vsm[0], wv, lane);
    __syncthreads();

    int cur = 0;
    for (int kt = 0; kt < ntile; ++kt) {
        const int key0 = kt * 64;
        if (kt + 1 < ntile)
            stage_kv(Kb, Vb, key0 + 64, Ksm[cur ^ 1], Vsm[cur ^ 1], wv, lane);

        f32x4 sacc[4] = {};
#pragma unroll
        for (int ks = 0; ks < 2; ++ks) {
#pragma unroll
            for (int kc = 0; kc < 4; ++kc) {
                const int rk = kc * 16 + qi;
                const bf16x8 ak = *(const bf16x8*)((const char*)Ksm[cur] + rk * 128 +
                                                   ((ks * 64 + g * 16) ^ xsw));
                sacc[kc] = __builtin_amdgcn_mfma_f32_16x16x32_bf16(ak, qf[ks], sacc[kc], 0, 0, 0);
            }
        }

        float p[4][4];
        float mymax = -1e30f;
        if (kt == ntile - 1) {
#pragma unroll
            for (int kc = 0; kc < 4; ++kc) {
#pragma unroll
                for (int r = 0; r < 4; ++r) {
                    const int key = key0 + kc * 16 + g * 4 + r;
                    float sv = sacc[kc][r];
                    if (key > qg) sv = -__builtin_inff();
                    p[kc][r] = sv;
                    mymax = fmaxf(mymax, sv);
                }
            }
        } else {
#pragma unroll
            for (int kc = 0; kc < 4; ++kc) {
#pragma unroll
                for (int r = 0; r < 4; ++r) {
                    p[kc][r] = sacc[kc][r];
                    mymax = fmaxf(mymax, sacc[kc][r]);
                }
            }
        }
        mymax = fmaxf(mymax, __shfl_xor(mymax, 16));
        mymax = fmaxf(mymax, __shfl_xor(mymax, 32));
        const float m_new = fmaxf(m_run, mymax);
        const float alpha = __expf(m_run - m_new);
        float lsum = 0.0f;
#pragma unroll
        for (int kc = 0; kc < 4; ++kc) {
#pragma unroll
            for (int r = 0; r < 4; ++r) {
                const float e = __expf(p[kc][r] - m_new);
                p[kc][r] = e;
                lsum += e;
            }
        }
        lsum += __shfl_xor(lsum, 16);
        lsum += __shfl_xor(lsum, 32);
        l_run = l_run * alpha + lsum;
        m_run = m_new;
#pragma unroll
        for (int c = 0; c < 4; ++c) {
#pragma unroll
            for (int r = 0; r < 4; ++r) oacc[c][r] *= alpha;
        }
#pragma unroll
        for (int kc = 0; kc < 4; ++kc) {
            u16x4 pk;
#pragma unroll
            for (int r = 0; r < 4; ++r) pk[r] = f2bf(p[kc][r]);
            *(u16x4*)(&Pl[wv][qi][kc * 16 + g * 4]) = pk;
        }
        bf16x8 pb[2];
#pragma unroll
        for (int ks = 0; ks < 2; ++ks)
            pb[ks] = *(const bf16x8*)(&Pl[wv][qi][ks * 32 + g * 8]);
#pragma unroll
        for (int ks = 0; ks < 2; ++ks) {
#pragma unroll
            for (int c = 0; c < 4; ++c) {
                const int rv = c * 16 + qi;
                const bf16x8 av = *(const bf16x8*)((const char*)Vsm[cur] + rv * 128 +
                                                   ((ks * 64 + g * 16) ^ xsw));
                oacc[c] = __builtin_amdgcn_mfma_f32_16x16x32_bf16(av, pb[ks], oacc[c], 0, 0, 0);
            }
        }
        __syncthreads();
        cur ^= 1;
    }

    const float inv = 1.0f / l_run;
#pragma unroll
    for (int c = 0; c < 4; ++c) {
        u16x4 o;
#pragma unroll
        for (int r = 0; r < 4; ++r) o[r] = f2bf(oacc[c][r] * inv);
        *(u16x4*)(&Y[((size_t)(b_ * 2048 + qg)) * 1024 + hh * 64 + c * 16 + g * 4]) = o;
    }
}

// ---------------- host ----------------
extern "C" void kernel_launch(void* const* d_in, const int* in_sizes, int n_in,
                              void* d_out, int out_size, void* d_ws, size_t ws_size,
                              hipStream_t stream) {
    (void)in_sizes; (void)n_in; (void)out_size;
    const float* x      = (const float*)d_in[0];
    const float* w_qkv  = (const float*)d_in[2];
    const float* b_qkv  = (const float*)d_in[3];
    const float* w_proj = (const float*)d_in[4];
    const float* b_proj = (const float*)d_in[5];
    const float* w_fc1  = (const float*)d_in[6];
    const float* b_fc1  = (const float*)d_in[7];
    const float* w_fc2  = (const float*)d_in[8];
    const float* b_fc2  = (const float*)d_in[9];
    const float* g1     = (const float*)d_in[10];
    const float* be1    = (const float*)d_in[11];
    const float* g2     = (const float*)d_in[12];
    const float* be2    = (const float*)d_in[13];

    char* ws = (char*)d_ws;
    size_t off = 0;
    auto alloc = [&](size_t bytes) { size_t r = off; off += (bytes + 255) & ~(size_t)255; return r; };
    u16*   wt_qkv = (u16*)(ws + alloc((size_t)3072 * 1024 * 2));
    u16*   wt_prj = (u16*)(ws + alloc((size_t)1024 * 1024 * 2));
    u16*   wt_fc1 = (u16*)(ws + alloc((size_t)4096 * 1024 * 2));
    u16*   wt_fc2 = (u16*)(ws + alloc((size_t)1024 * 4096 * 2));
    u16*   hbuf   = (u16*)(ws + alloc((size_t)4096 * 1024 * 2));
    float* x1     = (float*)(ws + alloc((size_t)4096 * 1024 * 4));
    char*  big    = ws + alloc((size_t)33554432);
    u16* qb  = (u16*)(big);
    u16* kb  = (u16*)(big + 8388608);
    u16* vtb = (u16*)(big + 16777216);
    u16* yb  = (u16*)(big + 25165824);
    u16* act = (u16*)(big);
    if (off > ws_size) return;
    const size_t part_need = (size_t)4 * 4096 * 1024 * 4;   // covers splitK=4 (FC2) and =2 (proj)
    if ((ws_size - off) < part_need) return;
    float* part = (float*)(ws + off);

    const dim3 blk(256);
    tcvt_kernel<<<dim3(32, 96), blk, 0, stream>>>(w_qkv, wt_qkv, 1024, 3072);
    tcvt_kernel<<<dim3(32, 32), blk, 0, stream>>>(w_proj, wt_prj, 1024, 1024);
    tcvt_kernel<<<dim3(32, 128), blk, 0, stream>>>(w_fc1, wt_fc1, 1024, 4096);
    tcvt_kernel<<<dim3(128, 32), blk, 0, stream>>>(w_fc2, wt_fc2, 4096, 1024);

    ln_kernel<<<dim3(4096), blk, 0, stream>>>(x, g1, be1, hbuf);
    // QKV: grid 32*24 = 768
    gemmv6<0, 1><<<dim3(768), blk, 0, stream>>>(hbuf, wt_qkv, b_qkv,
                                                qb, kb, vtb, 4096, 3072, 1024);
    attn_kernel<<<dim3(32, 32), blk, 0, stream>>>(qb, kb, vtb, yb);
    // proj split-K=2: grid 32*8*2 = 512, then reduce(+bias+x) -> x1
    gemmv6<4, 2><<<dim3(512), blk, 0, stream>>>(yb, wt_prj, nullptr,
                                                part, nullptr, nullptr, 4096, 1024, 1024);
    reduceN_kernel<2><<<dim3(4096), blk, 0, stream>>>(part, b_proj, x, x1, 1048576, 256);
    ln_kernel<<<dim3(4096), blk, 0, stream>>>(x1, g2, be2, hbuf);
    // FC1 + GELU: grid 32*32 = 1024
    gemmv6<2, 1><<<dim3(1024), blk, 0, stream>>>(hbuf, wt_fc1, b_fc1,
                                                 act, nullptr, nullptr, 4096, 4096, 1024);
    // FC2 split-K=4: grid 32*8*4 = 1024, then reduce(+bias+x1) -> d_out
    gemmv6<4, 4><<<dim3(1024), blk, 0, stream>>>(act, wt_fc2, nullptr,
                                                 part, nullptr, nullptr, 4096, 1024, 4096);
    reduceN_kernel<4><<<dim3(4096), blk, 0, stream>>>(part, b_fc2, x1, (float*)d_out,
                                                      1048576, 256);
}

// Round 7
// 249.452 us; speedup vs baseline: 1.3799x; 1.0842x over previous
//
#include <hip/hip_runtime.h>
#include <hip/hip_bf16.h>
#include <stdint.h>

typedef unsigned short u16;
typedef __attribute__((ext_vector_type(8))) short bf16x8;
typedef __attribute__((ext_vector_type(4))) float f32x4;
typedef __attribute__((ext_vector_type(16))) float f32x16;
typedef __attribute__((ext_vector_type(4))) unsigned short u16x4;

#define DEVI static __device__ __forceinline__

DEVI u16 f2bf(float f) {
    unsigned int u = __builtin_bit_cast(unsigned int, f);
    return (u16)((u + 0x7fffu + ((u >> 16) & 1u)) >> 16);
}

DEVI float gelu_f(float v) {
    // tanh-form GELU: x * sigmoid(1.5957691(x + 0.044715 x^3)); |err vs exact| <= ~3e-4
    const float z = 1.5957691216f * (v + 0.044715f * v * v * v);
    return v / (1.0f + __expf(-z));
}

DEVI void async_copy16(const void* g, void* l) {
    __builtin_amdgcn_global_load_lds((const __attribute__((address_space(1))) void*)g,
                                     (__attribute__((address_space(3))) void*)l,
                                     16, 0, 0);
}

// ---------------- weight transpose + f32->bf16 convert: src[K][N] -> dst[N][K] ----------------
__global__ __launch_bounds__(256) void tcvt_kernel(const float* __restrict__ src,
                                                   u16* __restrict__ dst,
                                                   int K, int N) {
    __shared__ float tile[32][33];
    const int k0 = blockIdx.x * 32, n0 = blockIdx.y * 32;
    const int t = threadIdx.x;
    const int c = t & 31, r0 = t >> 5;
#pragma unroll
    for (int p = 0; p < 4; ++p) {
        const int r = r0 + p * 8;
        tile[r][c] = src[(size_t)(k0 + r) * N + n0 + c];
    }
    __syncthreads();
#pragma unroll
    for (int p = 0; p < 4; ++p) {
        const int r = r0 + p * 8;
        dst[(size_t)(n0 + r) * K + k0 + c] = f2bf(tile[c][r]);
    }
}

// ---------------- LayerNorm (f32 in) -> bf16 out ----------------
__global__ __launch_bounds__(256) void ln_kernel(const float* __restrict__ x,
                                                 const float* __restrict__ gw,
                                                 const float* __restrict__ bw,
                                                 u16* __restrict__ out) {
    const int row = blockIdx.x;
    const int t = threadIdx.x;
    const float4 v = ((const float4*)(x + (size_t)row * 1024))[t];
    float s  = v.x + v.y + v.z + v.w;
    float ss = v.x * v.x + v.y * v.y + v.z * v.z + v.w * v.w;
#pragma unroll
    for (int off = 32; off > 0; off >>= 1) {
        s  += __shfl_down(s, off);
        ss += __shfl_down(ss, off);
    }
    __shared__ float red[8];
    const int wv = t >> 6;
    if ((t & 63) == 0) { red[wv] = s; red[4 + wv] = ss; }
    __syncthreads();
    if (t == 0) {
        red[0] = red[0] + red[1] + red[2] + red[3];
        red[4] = red[4] + red[5] + red[6] + red[7];
    }
    __syncthreads();
    const float mean = red[0] * (1.0f / 1024.0f);
    const float var  = red[4] * (1.0f / 1024.0f) - mean * mean;
    const float rstd = rsqrtf(var + 1e-5f);
    const float4 gv = ((const float4*)gw)[t];
    const float4 bv = ((const float4*)bw)[t];
    u16x4 o;
    o[0] = f2bf((v.x - mean) * rstd * gv.x + bv.x);
    o[1] = f2bf((v.y - mean) * rstd * gv.y + bv.y);
    o[2] = f2bf((v.z - mean) * rstd * gv.z + bv.z);
    o[3] = f2bf((v.w - mean) * rstd * gv.w + bv.w);
    ((u16x4*)out)[(size_t)row * 256 + t] = o;
}

// ================= 128x128 GEMM, BK=64, single-buffer, m97-pure schedule =================
DEVI void stage64(const char* g, size_t ldb, char* lds0, int lane, int wv) {
    const int colsw = ((lane & 3) << 4) ^ (lane & 32);  // inverse-swizzled source col bytes
    const int rl = lane >> 2;
#pragma unroll
    for (int i = 0; i < 4; ++i) {
        const int s = wv * 4 + i;            // slot 0..15
        const int kh = s >> 3, c = s & 7;    // k-half, 16-row subtile
        async_copy16(g + (size_t)(c * 16 + rl) * ldb + kh * 64 + colsw,
                     lds0 + s * 1024);
    }
}

// EPI 0: QKV scatter. EPI 2: gelu->bf16. EPI 4: f32 partial (split-K).
template <int EPI, int SPLITK>
__global__ __launch_bounds__(256, 4) void gemmv6(const u16* __restrict__ A,
                                                 const u16* __restrict__ Bt,
                                                 const float* __restrict__ bias,
                                                 void* __restrict__ out0,
                                                 void* __restrict__ out1,
                                                 void* __restrict__ out2,
                                                 int M, int N, int K) {
    __shared__ __align__(16) char As[16384];
    __shared__ __align__(16) char Bs[16384];
    const int tid = threadIdx.x;
    const int lane = tid & 63, wv = tid >> 6;
    const int wr = wv >> 1, wc = wv & 1;        // 2M x 2N waves, 64x64 each
    const int g = lane >> 4, qq = lane & 15;
    const int rdoff = qq * 64 + ((g * 16) ^ ((qq & 8) << 2));  // swizzled read offset

    const int nwg = gridDim.x;
    int id = blockIdx.x;
    id = (id & 7) * (nwg >> 3) + (id >> 3);
    const int MT = M >> 7, NTn = N >> 7;
    const int slice = id / (MT * NTn);
    const int r2 = id % (MT * NTn);
    const int m0 = (r2 % MT) << 7;
    const int n0 = (r2 / MT) << 7;
    const int Ks = K / SPLITK;
    const int NT = Ks >> 6;
    const size_t ldb = (size_t)K * 2;

    const char* pa = (const char*)A + (size_t)m0 * ldb + (size_t)slice * Ks * 2;
    const char* pb = (const char*)Bt + (size_t)n0 * ldb + (size_t)slice * Ks * 2;

    f32x4 acc[4][4] = {};

    for (int t = 0; t < NT; ++t) {
        stage64(pa + (size_t)t * 128, ldb, As, lane, wv);
        stage64(pb + (size_t)t * 128, ldb, Bs, lane, wv);
        __syncthreads();
#pragma unroll
        for (int kh = 0; kh < 2; ++kh) {
            bf16x8 fa[4], fb[4];
#pragma unroll
            for (int fn = 0; fn < 4; ++fn)
                fb[fn] = *(const bf16x8*)(Bs + (kh * 8 + wc * 4 + fn) * 1024 + rdoff);
#pragma unroll
            for (int fm = 0; fm < 4; ++fm)
                fa[fm] = *(const bf16x8*)(As + (kh * 8 + wr * 4 + fm) * 1024 + rdoff);
#pragma unroll
            for (int fm = 0; fm < 4; ++fm)
#pragma unroll
                for (int fn = 0; fn < 4; ++fn)
                    acc[fm][fn] = __builtin_amdgcn_mfma_f32_16x16x32_bf16(fa[fm], fb[fn],
                                                                          acc[fm][fn], 0, 0, 0);
        }
        __syncthreads();
    }

#pragma unroll
    for (int fm = 0; fm < 4; ++fm) {
#pragma unroll
        for (int fn = 0; fn < 4; ++fn) {
            const int mrow = m0 + wr * 64 + fm * 16 + g * 4;
            const int ncol = n0 + wc * 64 + fn * 16 + qq;
            if constexpr (EPI == 0) {
                const float bs = bias[ncol];
                const int sec = ncol >> 10;
                const int hd_ = ncol & 1023;
                const int hh = hd_ >> 6, dd = hd_ & 63;
                if (sec == 2) {
                    const int b_ = mrow >> 11, l_ = mrow & 2047;
                    u16x4 pk;
#pragma unroll
                    for (int r = 0; r < 4; ++r) pk[r] = f2bf(acc[fm][fn][r] + bs);
                    *(u16x4*)((u16*)out2 + ((size_t)((b_ * 16 + hh) * 64 + dd)) * 2048 + l_) = pk;
                } else {
                    u16* dst = (sec == 0) ? (u16*)out0 : (u16*)out1;
                    // q-scale folds softmax 1/sqrt(hd) AND log2(e) for exp2-domain softmax
                    const float sc = (sec == 0) ? 0.1803368801f : 1.0f;
#pragma unroll
                    for (int r = 0; r < 4; ++r) {
                        const int mr = mrow + r;
                        const int b_ = mr >> 11, l_ = mr & 2047;
                        dst[((size_t)((b_ * 16 + hh) * 2048 + l_)) * 64 + dd] =
                            f2bf((acc[fm][fn][r] + bs) * sc);
                    }
                }
            } else if constexpr (EPI == 2) {
                const float bs = bias[ncol];
                u16* dst = (u16*)out0;
#pragma unroll
                for (int r = 0; r < 4; ++r)
                    dst[(size_t)(mrow + r) * N + ncol] = f2bf(gelu_f(acc[fm][fn][r] + bs));
            } else {  // EPI 4: raw f32 partial for split-K
                float* dst = (float*)out0 + (size_t)slice * M * N;
#pragma unroll
                for (int r = 0; r < 4; ++r)
                    dst[(size_t)(mrow + r) * N + ncol] = acc[fm][fn][r];
            }
        }
    }
}

// split-K reduce + bias + residual -> f32 out
template <int SPLIT>
__global__ __launch_bounds__(256) void reduceN_kernel(const float* __restrict__ p,
                                                      const float* __restrict__ bias,
                                                      const float* __restrict__ res,
                                                      float* __restrict__ out,
                                                      int MN4, int N4) {
    const int i = blockIdx.x * 256 + threadIdx.x;   // one float4
    float4 s = ((const float4*)p)[i];
#pragma unroll
    for (int s2 = 1; s2 < SPLIT; ++s2) {
        const float4 q = ((const float4*)p)[(size_t)s2 * MN4 + i];
        s.x += q.x; s.y += q.y; s.z += q.z; s.w += q.w;
    }
    const float4 r = ((const float4*)res)[i];
    const float4 bs = ((const float4*)bias)[i & (N4 - 1)];
    float4 o;
    o.x = s.x + r.x + bs.x;
    o.y = s.y + r.y + bs.y;
    o.z = s.z + r.z + bs.z;
    o.w = s.w + r.w + bs.w;
    ((float4*)out)[i] = o;
}

// ---------------- causal flash attention v2: 32 q-rows/wave, 32x32x16 MFMA ----------------
// Q [BH][2048][64] (pre-scaled by 0.125*log2e), K [BH][2048][64], Vt [BH][64][2048].
// Block = 4 waves x 32 q-rows = 128 rows; triangle-paired: block bx does q-chunk (15-bx) then bx
// -> uniform 36 KV-tiles per block. Swapped S^T = K*Q^T so each lane owns col q=lane&31;
// lane and lane+32 split the 64 keys (C-layout row=(r&3)+8*(r>>2)+4*hi). Softmax in exp2 domain,
// defer-max THR=11 (T13). P staged via per-wave padded LDS [32][72]. K/V LDS staging identical
// to the HW-verified round-1 kernel.
DEVI void stage_kv(const char* kbase, const char* vbase, int key0,
                   u16* ksm, u16* vsm, int wv, int lane) {
#pragma unroll
    for (int i = 0; i < 2; ++i) {
        const int c = wv + i * 4;
        const int off = c * 1024 + lane * 16;
        const int row = off >> 7;
        const int scol = (off & 127) ^ ((row & 7) << 4);
        async_copy16(kbase + (size_t)key0 * 128 + (size_t)row * 128 + scol,
                     (char*)ksm + c * 1024);
    }
#pragma unroll
    for (int i = 0; i < 2; ++i) {
        const int c = wv + i * 4;
        const int row = c * 8 + (lane >> 3);
        const int scol = ((lane & 7) * 16) ^ ((row & 7) << 4);
        async_copy16(vbase + (size_t)row * 4096 + (size_t)key0 * 2 + scol,
                     (char*)vsm + c * 1024);
    }
}

__global__ __launch_bounds__(256, 3) void attn32_kernel(const u16* __restrict__ Q,
                                                        const u16* __restrict__ Kk,
                                                        const u16* __restrict__ Vt,
                                                        u16* __restrict__ Y) {
    const int bh = blockIdx.y;
    const int b_ = bh >> 4, hh = bh & 15;
    const int bx = blockIdx.x;                 // 0..7
    const int tid = threadIdx.x;
    const int wv = tid >> 6, lane = tid & 63;
    const int hi = lane >> 5, qc = lane & 31;

    __shared__ __align__(16) u16 Ksm[2][4096];
    __shared__ __align__(16) u16 Vsm[2][4096];
    __shared__ __align__(16) u16 Pl[4][32 * 72];   // per-wave P[q][key], stride 72 u16

    const char* Kb = (const char*)(Kk + (size_t)bh * 2048 * 64);
    const char* Vb = (const char*)(Vt + (size_t)bh * 64 * 2048);
    u16* Pw = &Pl[wv][0];
    const u16* Pr = Pw + qc * 72;

#pragma unroll 1
    for (int part = 0; part < 2; ++part) {
        const int qb = part ? bx : (15 - bx);    // large chunk first
        const int q0w = qb * 128 + wv * 32;
        const int qg = q0w + qc;
        const int ntile = qb * 2 + 2;
        const int ntile_w = qb * 2 + (wv >> 1) + 1;   // per-wave causal clamp

        bf16x8 qf[4];
        {
            const u16* Qp = Q + ((size_t)bh * 2048 + q0w + qc) * 64;
#pragma unroll
            for (int c = 0; c < 4; ++c)
                qf[c] = *(const bf16x8*)(Qp + c * 16 + hi * 8);
        }

        f32x16 oacc[2];
#pragma unroll
        for (int r = 0; r < 16; ++r) { oacc[0][r] = 0.0f; oacc[1][r] = 0.0f; }
        float m_run = -1e30f, l_run = 0.0f;

        stage_kv(Kb, Vb, 0, Ksm[0], Vsm[0], wv, lane);
        __syncthreads();
        int cur = 0;
        for (int kt = 0; kt < ntile; ++kt) {
            const int key0 = kt * 64;
            if (kt + 1 < ntile)
                stage_kv(Kb, Vb, key0 + 64, Ksm[cur ^ 1], Vsm[cur ^ 1], wv, lane);
            if (kt < ntile_w) {
                // S^T = K * Q^T
                f32x16 sacc[2];
#pragma unroll
                for (int r = 0; r < 16; ++r) { sacc[0][r] = 0.0f; sacc[1][r] = 0.0f; }
#pragma unroll
                for (int c = 0; c < 4; ++c) {
#pragma unroll
                    for (int kb = 0; kb < 2; ++kb) {
                        const int kr = kb * 32 + qc;
                        const bf16x8 ak = *(const bf16x8*)((const char*)Ksm[cur] + kr * 128 +
                                              ((c * 32 + hi * 16) ^ ((kr & 7) << 4)));
                        sacc[kb] = __builtin_amdgcn_mfma_f32_32x32x16_bf16(ak, qf[c],
                                                                           sacc[kb], 0, 0, 0);
                    }
                }
                // causal mask (only tiles overlapping the diagonal) + row max
                float pmax = -1e30f;
                if (key0 + 63 > q0w) {
#pragma unroll
                    for (int kb = 0; kb < 2; ++kb)
#pragma unroll
                        for (int r = 0; r < 16; ++r) {
                            const int key = key0 + kb * 32 + (r & 3) + 8 * (r >> 2) + 4 * hi;
                            float s = sacc[kb][r];
                            if (key > qg) s = -1e30f;
                            sacc[kb][r] = s;
                            pmax = fmaxf(pmax, s);
                        }
                } else {
#pragma unroll
                    for (int kb = 0; kb < 2; ++kb)
#pragma unroll
                        for (int r = 0; r < 16; ++r) pmax = fmaxf(pmax, sacc[kb][r]);
                }
                pmax = fmaxf(pmax, __shfl_xor(pmax, 32));
                if (pmax > m_run + 11.0f) {          // defer-max: skip rescale when close
                    const float alpha = __builtin_amdgcn_exp2f(m_run - pmax);
#pragma unroll
                    for (int r = 0; r < 16; ++r) { oacc[0][r] *= alpha; oacc[1][r] *= alpha; }
                    l_run *= alpha;
                    m_run = pmax;
                }
                float lsum = 0.0f;
#pragma unroll
                for (int kb = 0; kb < 2; ++kb)
#pragma unroll
                    for (int j = 0; j < 4; ++j) {
                        u16x4 pk4;
#pragma unroll
                        for (int t = 0; t < 4; ++t) {
                            const float e = __builtin_amdgcn_exp2f(sacc[kb][j * 4 + t] - m_run);
                            lsum += e;
                            pk4[t] = f2bf(e);
                        }
                        *(u16x4*)(Pw + qc * 72 + kb * 32 + j * 8 + 4 * hi) = pk4;
                    }
                lsum += __shfl_xor(lsum, 32);
                l_run += lsum;
                // O^T += V^T * P
#pragma unroll
                for (int c = 0; c < 4; ++c) {
                    const bf16x8 pf = *(const bf16x8*)(Pr + c * 16 + hi * 8);
#pragma unroll
                    for (int db = 0; db < 2; ++db) {
                        const int dr = db * 32 + qc;
                        const bf16x8 av = *(const bf16x8*)((const char*)Vsm[cur] + dr * 128 +
                                              ((c * 32 + hi * 16) ^ ((dr & 7) << 4)));
                        oacc[db] = __builtin_amdgcn_mfma_f32_32x32x16_bf16(av, pf,
                                                                           oacc[db], 0, 0, 0);
                    }
                }
            }
            __syncthreads();
            cur ^= 1;
        }
        const float inv = 1.0f / l_run;
        u16* Yp = &Y[((size_t)(b_ * 2048 + qg)) * 1024 + hh * 64];
#pragma unroll
        for (int db = 0; db < 2; ++db)
#pragma unroll
            for (int j = 0; j < 4; ++j) {
                u16x4 o;
#pragma unroll
                for (int t = 0; t < 4; ++t) o[t] = f2bf(oacc[db][j * 4 + t] * inv);
                *(u16x4*)(Yp + db * 32 + j * 8 + 4 * hi) = o;
            }
    }
}

// ---------------- host ----------------
extern "C" void kernel_launch(void* const* d_in, const int* in_sizes, int n_in,
                              void* d_out, int out_size, void* d_ws, size_t ws_size,
                              hipStream_t stream) {
    (void)in_sizes; (void)n_in; (void)out_size;
    const float* x      = (const float*)d_in[0];
    const float* w_qkv  = (const float*)d_in[2];
    const float* b_qkv  = (const float*)d_in[3];
    const float* w_proj = (const float*)d_in[4];
    const float* b_proj = (const float*)d_in[5];
    const float* w_fc1  = (const float*)d_in[6];
    const float* b_fc1  = (const float*)d_in[7];
    const float* w_fc2  = (const float*)d_in[8];
    const float* b_fc2  = (const float*)d_in[9];
    const float* g1     = (const float*)d_in[10];
    const float* be1    = (const float*)d_in[11];
    const float* g2     = (const float*)d_in[12];
    const float* be2    = (const float*)d_in[13];

    char* ws = (char*)d_ws;
    size_t off = 0;
    auto alloc = [&](size_t bytes) { size_t r = off; off += (bytes + 255) & ~(size_t)255; return r; };
    u16*   wt_qkv = (u16*)(ws + alloc((size_t)3072 * 1024 * 2));
    u16*   wt_prj = (u16*)(ws + alloc((size_t)1024 * 1024 * 2));
    u16*   wt_fc1 = (u16*)(ws + alloc((size_t)4096 * 1024 * 2));
    u16*   wt_fc2 = (u16*)(ws + alloc((size_t)1024 * 4096 * 2));
    u16*   hbuf   = (u16*)(ws + alloc((size_t)4096 * 1024 * 2));
    float* x1     = (float*)(ws + alloc((size_t)4096 * 1024 * 4));
    char*  big    = ws + alloc((size_t)33554432);
    u16* qb  = (u16*)(big);
    u16* kb  = (u16*)(big + 8388608);
    u16* vtb = (u16*)(big + 16777216);
    u16* yb  = (u16*)(big + 25165824);
    u16* act = (u16*)(big);
    if (off > ws_size) return;
    const size_t part_need = (size_t)4 * 4096 * 1024 * 4;
    if ((ws_size - off) < part_need) return;
    float* part = (float*)(ws + off);

    const dim3 blk(256);
    tcvt_kernel<<<dim3(32, 96), blk, 0, stream>>>(w_qkv, wt_qkv, 1024, 3072);
    tcvt_kernel<<<dim3(32, 32), blk, 0, stream>>>(w_proj, wt_prj, 1024, 1024);
    tcvt_kernel<<<dim3(32, 128), blk, 0, stream>>>(w_fc1, wt_fc1, 1024, 4096);
    tcvt_kernel<<<dim3(128, 32), blk, 0, stream>>>(w_fc2, wt_fc2, 4096, 1024);

    ln_kernel<<<dim3(4096), blk, 0, stream>>>(x, g1, be1, hbuf);
    // QKV: grid 32*24 = 768
    gemmv6<0, 1><<<dim3(768), blk, 0, stream>>>(hbuf, wt_qkv, b_qkv,
                                                qb, kb, vtb, 4096, 3072, 1024);
    // attention v2: 8 paired q-blocks x 32 bh
    attn32_kernel<<<dim3(8, 32), blk, 0, stream>>>(qb, kb, vtb, yb);
    // proj split-K=2: grid 32*8*2 = 512, then reduce(+bias+x) -> x1
    gemmv6<4, 2><<<dim3(512), blk, 0, stream>>>(yb, wt_prj, nullptr,
                                                part, nullptr, nullptr, 4096, 1024, 1024);
    reduceN_kernel<2><<<dim3(4096), blk, 0, stream>>>(part, b_proj, x, x1, 1048576, 256);
    ln_kernel<<<dim3(4096), blk, 0, stream>>>(x1, g2, be2, hbuf);
    // FC1 + GELU: grid 32*32 = 1024
    gemmv6<2, 1><<<dim3(1024), blk, 0, stream>>>(hbuf, wt_fc1, b_fc1,
                                                 act, nullptr, nullptr, 4096, 4096, 1024);
    // FC2 split-K=4: grid 32*8*4 = 1024, then reduce(+bias+x1) -> d_out
    gemmv6<4, 4><<<dim3(1024), blk, 0, stream>>>(act, wt_fc2, nullptr,
                                                 part, nullptr, nullptr, 4096, 1024, 4096);
    reduceN_kernel<4><<<dim3(4096), blk, 0, stream>>>(part, b_fc2, x1, (float*)d_out,
                                                      1048576, 256);
}